// Round 8
// baseline (2223.494 us; speedup 1.0000x reference)
//
#include <hip/hip_runtime.h>
#include <cstddef>

#define BATCH   8
#define LSEQ    4096
#define DMODEL  128
#define DINNER  256
#define NSTATE  16
#define NLAYER  4
#define MROWS   (BATCH*LSEQ)   // 32768

__device__ __forceinline__ float silu_f(float v) { return v / (1.f + expf(-v)); }
__device__ __forceinline__ float softplus_f(float v) {
  return v > 20.f ? v : log1pf(expf(v));
}

// ---------------------------------------------------------------------------
// Generic tiled GEMM: C = A[M,K] @ W[N,K]^T
// ---------------------------------------------------------------------------
__global__ __launch_bounds__(256) void gemm_awt(
    const float* __restrict__ A, const float* __restrict__ W,
    float* __restrict__ out0, float* __restrict__ out1,
    int M, int N, int K, int mode)
{
  __shared__ float As[32][68];
  __shared__ float Bs[32][68];
  const int m0 = blockIdx.x * 64;
  const int n0 = blockIdx.y * 64;
  const int t  = threadIdx.x;
  const int tx = t & 15, ty = t >> 4;
  const int kk_s = t & 31, row_s = t >> 5;

  float acc[4][4] = {};

  for (int k0 = 0; k0 < K; k0 += 32) {
#pragma unroll
    for (int p = 0; p < 8; ++p) {
      int r = row_s + p * 8;
      As[kk_s][r] = A[(size_t)(m0 + r) * K + (k0 + kk_s)];
      Bs[kk_s][r] = W[(size_t)(n0 + r) * K + (k0 + kk_s)];
    }
    __syncthreads();
#pragma unroll
    for (int kk = 0; kk < 32; ++kk) {
      float4 a4 = *(const float4*)&As[kk][ty * 4];
      float4 b4 = *(const float4*)&Bs[kk][tx * 4];
      float av[4] = {a4.x, a4.y, a4.z, a4.w};
      float bv[4] = {b4.x, b4.y, b4.z, b4.w};
#pragma unroll
      for (int i = 0; i < 4; ++i)
#pragma unroll
        for (int j = 0; j < 4; ++j)
          acc[i][j] = fmaf(av[i], bv[j], acc[i][j]);
    }
    __syncthreads();
  }

#pragma unroll
  for (int i = 0; i < 4; ++i) {
    int m = m0 + ty * 4 + i;
    float4 c4 = make_float4(acc[i][0], acc[i][1], acc[i][2], acc[i][3]);
    if (mode == 0) {
      *(float4*)&out0[(size_t)m * N + n0 + tx * 4] = c4;
    } else {
      int n = n0 + tx * 4;
      if (n < 256) {
        *(float4*)&out0[(size_t)m * 256 + n] = c4;
      } else {
        c4.x = silu_f(c4.x); c4.y = silu_f(c4.y);
        c4.z = silu_f(c4.z); c4.w = silu_f(c4.w);
        *(float4*)&out1[(size_t)m * 256 + (n - 256)] = c4;
      }
    }
  }
}

// ---------------------------------------------------------------------------
// Causal depthwise conv (k=4) + bias + silu, with [M,256] -> [B,256,L] transpose
// ---------------------------------------------------------------------------
__global__ __launch_bounds__(256) void conv_silu_t(
    const float* __restrict__ xa_rm,   // [M,256]
    const float* __restrict__ cw,      // [256,4]
    const float* __restrict__ cb,      // [256]
    float* __restrict__ xa_t)          // [B,256,L]
{
  __shared__ float tile[64][133];      // [dd][li], li=0 ~ l0-3
  __shared__ float s_cw[64][4];
  __shared__ float s_cb[64];
  const int b  = blockIdx.z;
  const int d0 = blockIdx.y * 64;
  const int l0 = blockIdx.x * 128;
  const int t  = threadIdx.x;

  if (t < 64) {
    s_cb[t] = cb[d0 + t];
#pragma unroll
    for (int k = 0; k < 4; ++k) s_cw[t][k] = cw[(d0 + t) * 4 + k];
  }
  const int dd_st = t & 63;
  for (int li = t >> 6; li < 131; li += 4) {
    int l = l0 - 3 + li;
    float v = 0.f;
    if (l >= 0) v = xa_rm[((size_t)(b * LSEQ + l)) * 256 + d0 + dd_st];
    tile[dd_st][li] = v;
  }
  __syncthreads();

  for (int idx = t; idx < 64 * 128; idx += 256) {
    int dd = idx >> 7;
    int lc = idx & 127;
    float v = s_cb[dd]
            + tile[dd][lc + 0] * s_cw[dd][0]
            + tile[dd][lc + 1] * s_cw[dd][1]
            + tile[dd][lc + 2] * s_cw[dd][2]
            + tile[dd][lc + 3] * s_cw[dd][3];
    v = silu_f(v);
    xa_t[((size_t)(b * DINNER + d0 + dd)) * LSEQ + l0 + lc] = v;
  }
}

// ---------------------------------------------------------------------------
// Fused x_proj (40x256) + dt_proj (256x8) + softplus.
// Writes dt_t [B,256,L], Bt/Ct [B,16,L]  (state-major, L-contiguous).
// ---------------------------------------------------------------------------
__global__ __launch_bounds__(256) void proj_dt(
    const float* __restrict__ xa_t,    // [B,256,L]
    const float* __restrict__ xp_w,    // [40,256]
    const float* __restrict__ dtp_w,   // [256,8]
    const float* __restrict__ dtp_b,   // [256]
    float* __restrict__ dt_t,          // [B,256,L]
    float* __restrict__ Bt,            // [B,16,L]
    float* __restrict__ Ct)            // [B,16,L]
{
  __shared__ float s_xpc[40][68];
  __shared__ float s_dtw[256 * 8];
  __shared__ float s_dtb[256];
  __shared__ float s_xa[64][68];
  __shared__ float s_proj[64][44];
  const int b  = blockIdx.y;
  const int l0 = blockIdx.x * 64;
  const int t  = threadIdx.x;

  for (int i = t; i < 256 * 8; i += 256) s_dtw[i] = dtp_w[i];
  s_dtb[t] = dtp_b[t];

  const int ll_st  = t & 63;
  const int kk0_st = t >> 6;
  const int kk_w   = t & 63;
  const int nb_w   = t >> 6;
  const int lA = t & 31;
  const int g  = t >> 5;

  float acc0[5] = {}, acc1[5] = {};

  for (int kc = 0; kc < 256; kc += 64) {
    __syncthreads();
#pragma unroll
    for (int p = 0; p < 16; ++p) {
      int kk = kk0_st + p * 4;
      s_xa[ll_st][kk] =
          xa_t[((size_t)(b * DINNER + kc + kk)) * LSEQ + l0 + ll_st];
    }
#pragma unroll
    for (int p = 0; p < 10; ++p) {
      int n = nb_w + p * 4;
      s_xpc[n][kk_w] = xp_w[n * 256 + kc + kk_w];
    }
    __syncthreads();
#pragma unroll
    for (int kk = 0; kk < 64; kk += 4) {
      float4 a0 = *(const float4*)&s_xa[lA][kk];
      float4 a1 = *(const float4*)&s_xa[lA + 32][kk];
#pragma unroll
      for (int j = 0; j < 5; ++j) {
        float4 w4 = *(const float4*)&s_xpc[g * 5 + j][kk];
        acc0[j] = fmaf(a0.x, w4.x, fmaf(a0.y, w4.y,
                  fmaf(a0.z, w4.z, fmaf(a0.w, w4.w, acc0[j]))));
        acc1[j] = fmaf(a1.x, w4.x, fmaf(a1.y, w4.y,
                  fmaf(a1.z, w4.z, fmaf(a1.w, w4.w, acc1[j]))));
      }
    }
  }
  __syncthreads();
#pragma unroll
  for (int j = 0; j < 5; ++j) {
    s_proj[lA][g * 5 + j]      = acc0[j];
    s_proj[lA + 32][g * 5 + j] = acc1[j];
  }
  __syncthreads();

  const int ll = t & 63;
  const int dgroup = t >> 6;
  float4 p0 = *(const float4*)&s_proj[ll][0];
  float4 p1 = *(const float4*)&s_proj[ll][4];
  for (int j = 0; j < 64; ++j) {
    int dout = dgroup * 64 + j;
    float4 w0 = *(const float4*)&s_dtw[dout * 8];
    float4 w1 = *(const float4*)&s_dtw[dout * 8 + 4];
    float v = s_dtb[dout]
            + p0.x * w0.x + p0.y * w0.y + p0.z * w0.z + p0.w * w0.w
            + p1.x * w1.x + p1.y * w1.y + p1.z * w1.z + p1.w * w1.w;
    dt_t[((size_t)(b * DINNER + dout)) * LSEQ + l0 + ll] = softplus_f(v);
  }
  // Bt/Ct: [B,16,L] — 64 consecutive l-addresses per instruction (coalesced)
  if (t < 64) {
#pragma unroll
    for (int nn = 0; nn < 16; ++nn)
      Bt[((size_t)(b * NSTATE + nn)) * LSEQ + l0 + t] = s_proj[t][8 + nn];
  } else if (t < 128) {
    int lw = t - 64;
#pragma unroll
    for (int nn = 0; nn < 16; ++nn)
      Ct[((size_t)(b * NSTATE + nn)) * LSEQ + l0 + lw] = s_proj[lw][24 + nn];
  }
}

// ---------------------------------------------------------------------------
// Selective scan — EXACT sequential recurrence, bit-identical arithmetic to
// R7 (absmax 1.455e-11). m97-style DMA pipeline: per 64-step chunk, the
// block's 2 waves issue 12 global_load_lds (16B-wide) staging dt/u/B/C into
// a double-buffered 12KB LDS buffer, then __syncthreads (its vmcnt drain is
// absorbed: chunk compute ~1500cyc >> load latency). No VGPR staging exists,
// so the compiler cannot sink the prefetch (R6/R7 failure mode).
// XOR quad-swizzle on the DMA *source* address keeps the LDS dest contiguous
// (wave-uniform-base constraint) while making the 16 state-row b128 reads
// 2-way-aliased (free, m136): slot q_st holds global quad q_st^(row&15);
// compute reads offset 4*(q^row).
// Block: 128 thr = 2 waves, 8 channels of one batch; 16 lanes (one per
// state) per channel. Grid: 8*32 = 256 blocks.
// ---------------------------------------------------------------------------
#define SCHUNK  64                 // steps per staged chunk
#define NCHUNKS (LSEQ / SCHUNK)    // 64
#define LDT 0                      // float offsets inside one LDS buffer
#define LU  512                    //   dt[8][64], u[8][64]
#define LB  1024                   //   B[16][64]
#define LC  2048                   //   C[16][64]
#define LBUF 3072                  // floats per buffer (12KB)

typedef __attribute__((address_space(3))) void       lds_vp;
typedef const __attribute__((address_space(1))) void glb_vp;

__global__ __launch_bounds__(128) void scan_k(
    const float* __restrict__ dt_t, const float* __restrict__ u_t,
    const float* __restrict__ Bt,   const float* __restrict__ Ct,
    const float* __restrict__ A_log, const float* __restrict__ Dp,
    float* __restrict__ y_t)
{
  __shared__ float lds[2 * LBUF];
  const int blk = blockIdx.x;
  const int b   = blk >> 5;
  const int ch0 = (blk & 31) * 8;
  const int tid  = threadIdx.x;
  const int wave = tid >> 6;
  const int lane = tid & 63;
  const int g = lane >> 4;
  const int n = lane & 15;
  const int d = ch0 + wave * 4 + g;      // channel index in [0,256)
  const int r_dt = wave * 4 + g;         // dt/u LDS row (0..7)

  const float Aa = -expf(A_log[d * NSTATE + n]);
  const float Dv = Dp[d];

  const float* dtg = dt_t + ((size_t)b * DINNER + ch0) * LSEQ;
  const float* ug  = u_t  + ((size_t)b * DINNER + ch0) * LSEQ;
  const float* Bg  = Bt + (size_t)b * NSTATE * LSEQ;
  const float* Cg  = Ct + (size_t)b * NSTATE * LSEQ;
  float4* yp = (float4*)(y_t + ((size_t)(b * DINNER + d)) * LSEQ);

  const int sR = lane >> 4;              // staging: relative row 0..3
  const int sq = lane & 15;              // staging: dest quad

  float h = 0.f;

#define STAGE(cbuf, chunk) do {                                            \
    float* Lb = lds + (cbuf) * LBUF;                                       \
    const int _c64 = (chunk) * SCHUNK;                                     \
    if (wave == 0) {                                                       \
      _Pragma("unroll")                                                    \
      for (int i = 0; i < 2; ++i) {                                        \
        int Rr = i * 4 + sR;                                               \
        const float* gp = dtg + (size_t)Rr * LSEQ + _c64 + 4 * (sq ^ Rr);  \
        __builtin_amdgcn_global_load_lds((glb_vp*)gp,                      \
            (lds_vp*)(Lb + LDT + i * 256), 16, 0, 0);                      \
      }                                                                    \
      _Pragma("unroll")                                                    \
      for (int i = 0; i < 4; ++i) {                                        \
        int Rr = i * 4 + sR;                                               \
        const float* gp = Bg + (size_t)Rr * LSEQ + _c64 + 4 * (sq ^ Rr);   \
        __builtin_amdgcn_global_load_lds((glb_vp*)gp,                      \
            (lds_vp*)(Lb + LB + i * 256), 16, 0, 0);                       \
      }                                                                    \
    } else {                                                               \
      _Pragma("unroll")                                                    \
      for (int i = 0; i < 2; ++i) {                                        \
        int Rr = i * 4 + sR;                                               \
        const float* gp = ug + (size_t)Rr * LSEQ + _c64 + 4 * (sq ^ Rr);   \
        __builtin_amdgcn_global_load_lds((glb_vp*)gp,                      \
            (lds_vp*)(Lb + LU + i * 256), 16, 0, 0);                       \
      }                                                                    \
      _Pragma("unroll")                                                    \
      for (int i = 0; i < 4; ++i) {                                        \
        int Rr = i * 4 + sR;                                               \
        const float* gp = Cg + (size_t)Rr * LSEQ + _c64 + 4 * (sq ^ Rr);   \
        __builtin_amdgcn_global_load_lds((glb_vp*)gp,                      \
            (lds_vp*)(Lb + LC + i * 256), 16, 0, 0);                       \
      }                                                                    \
    }                                                                      \
  } while (0)

#define LOADG(s, cbuf, t) do {                                             \
    const float* Lb = lds + (cbuf) * LBUF;                                 \
    _Pragma("unroll")                                                      \
    for (int q = 0; q < 2; ++q) {                                          \
      int qq = (t) * 2 + q;                                                \
      Rd[s][q] = *(const float4*)(Lb + LDT + r_dt * 64 + 4 * (qq ^ r_dt)); \
      Ru[s][q] = *(const float4*)(Lb + LU  + r_dt * 64 + 4 * (qq ^ r_dt)); \
      Rb[s][q] = *(const float4*)(Lb + LB  + n * 64    + 4 * (qq ^ n));    \
      Rc[s][q] = *(const float4*)(Lb + LC  + n * 64    + 4 * (qq ^ n));    \
    }                                                                      \
  } while (0)

#define COMPG(s, c, t) do {                                                \
    float p[8], us8[8];                                                    \
    _Pragma("unroll")                                                      \
    for (int q = 0; q < 2; ++q) {                                          \
      float dts[4] = {Rd[s][q].x, Rd[s][q].y, Rd[s][q].z, Rd[s][q].w};     \
      float uq[4]  = {Ru[s][q].x, Ru[s][q].y, Ru[s][q].z, Ru[s][q].w};     \
      float bv[4]  = {Rb[s][q].x, Rb[s][q].y, Rb[s][q].z, Rb[s][q].w};     \
      float cv[4]  = {Rc[s][q].x, Rc[s][q].y, Rc[s][q].z, Rc[s][q].w};     \
      _Pragma("unroll")                                                    \
      for (int st = 0; st < 4; ++st) {                                     \
        int i = q * 4 + st;                                                \
        float a = expf(dts[st] * Aa);                                      \
        h = fmaf(a, h, (dts[st] * uq[st]) * bv[st]);                       \
        p[i] = h * cv[st];                                                 \
        us8[i] = uq[st];                                                   \
      }                                                                    \
    }                                                                      \
    _Pragma("unroll")                                                      \
    for (int i = 0; i < 8; ++i) p[i] += __shfl_xor(p[i], 1);               \
    _Pragma("unroll")                                                      \
    for (int i = 0; i < 8; ++i) p[i] += __shfl_xor(p[i], 2);               \
    _Pragma("unroll")                                                      \
    for (int i = 0; i < 8; ++i) p[i] += __shfl_xor(p[i], 4);               \
    _Pragma("unroll")                                                      \
    for (int i = 0; i < 8; ++i) p[i] += __shfl_xor(p[i], 8);               \
    if (n == 0) {                                                          \
      _Pragma("unroll")                                                    \
      for (int q = 0; q < 2; ++q)                                          \
        yp[((c) * 8 + (t)) * 2 + q] = make_float4(                         \
            fmaf(us8[q*4+0], Dv, p[q*4+0]),                                \
            fmaf(us8[q*4+1], Dv, p[q*4+1]),                                \
            fmaf(us8[q*4+2], Dv, p[q*4+2]),                                \
            fmaf(us8[q*4+3], Dv, p[q*4+3]));                               \
    }                                                                      \
  } while (0)

  STAGE(0, 0);
  for (int c = 0; c < NCHUNKS; ++c) {
    const int cb = c & 1;
    __syncthreads();                   // drains DMA for chunk c (landed
    if (c + 1 < NCHUNKS)               // during previous chunk's compute)
      STAGE(cb ^ 1, c + 1);
    float4 Rd[2][2], Ru[2][2], Rb[2][2], Rc[2][2];
    LOADG(0, cb, 0);
#pragma unroll
    for (int t = 0; t < 7; ++t) {
      LOADG((t + 1) & 1, cb, t + 1);   // 1-group LDS lookahead
      COMPG(t & 1, c, t);
    }
    COMPG(1, c, 7);
  }
#undef STAGE
#undef LOADG
#undef COMPG
}

// ---------------------------------------------------------------------------
// ymul[m,d] = y_t[b,d,l] * zs[m,d]   ([B,256,L] -> [M,256] transpose, fused mul)
// ---------------------------------------------------------------------------
__global__ __launch_bounds__(256) void transmul(
    const float* __restrict__ y_t, const float* __restrict__ zs,
    float* __restrict__ outA)
{
  __shared__ float tile[64][129];
  const int b  = blockIdx.z;
  const int d0 = blockIdx.y * 64;
  const int l0 = blockIdx.x * 128;
  const int t  = threadIdx.x;
  const int lc_st = t & 127;
  for (int dd = t >> 7; dd < 64; dd += 2)
    tile[dd][lc_st] = y_t[((size_t)(b * DINNER + d0 + dd)) * LSEQ + l0 + lc_st];
  __syncthreads();
  for (int idx = t; idx < 64 * 128; idx += 256) {
    int dd = idx & 63, lc = idx >> 6;
    size_t addr = ((size_t)(b * LSEQ) + l0 + lc) * DINNER + d0 + dd;
    outA[addr] = tile[dd][lc] * zs[addr];
  }
}

// ---------------------------------------------------------------------------
extern "C" void kernel_launch(void* const* d_in, const int* in_sizes, int n_in,
                              void* d_out, int out_size, void* d_ws, size_t ws_size,
                              hipStream_t stream) {
  const float* x_in  = (const float*)d_in[0];
  const float* w_in  = (const float*)d_in[1];   // [4,512,128]
  const float* cw    = (const float*)d_in[2];   // [4,256,4]
  const float* cb    = (const float*)d_in[3];   // [4,256]
  const float* xpw   = (const float*)d_in[4];   // [4,40,256]
  const float* dtw   = (const float*)d_in[5];   // [4,256,8]
  const float* dtb   = (const float*)d_in[6];   // [4,256]
  const float* alog  = (const float*)d_in[7];   // [4,256,16]
  const float* Dp    = (const float*)d_in[8];   // [4,256]
  const float* ow    = (const float*)d_in[9];   // [4,128,256]
  float* out = (float*)d_out;

  const size_t M = MROWS;
  float* f0 = (float*)d_ws;            // x ping  [M,128]
  float* f1 = f0 + M * 128;            // x pong  [M,128]
  float* f2 = f1 + M * 128;            // xa_pre -> dt_t [B,256,L]
  float* f3 = f2 + M * 256;            // zs = silu(z) [M,256]
  float* f4 = f3 + M * 256;            // xa_t [B,256,L] -> later ymul [M,256]
  float* f6 = f4 + M * 256;            // Bt [B,16,L]
  float* f7 = f6 + M * 16;             // Ct [B,16,L]
  float* f8 = f7 + M * 16;             // y_t [B,256,L]

  const float* cur = x_in;
  for (int i = 0; i < NLAYER; ++i) {
    float* xout = (i == NLAYER - 1) ? out : ((i % 2 == 0) ? f0 : f1);
    const float* wi  = w_in + (size_t)i * 512 * 128;
    const float* cwi = cw   + (size_t)i * 256 * 4;
    const float* cbi = cb   + (size_t)i * 256;
    const float* xpi = xpw  + (size_t)i * 40 * 256;
    const float* dwi = dtw  + (size_t)i * 256 * 8;
    const float* dbi = dtb  + (size_t)i * 256;
    const float* ali = alog + (size_t)i * 256 * 16;
    const float* dpi = Dp   + (size_t)i * 256;
    const float* owi = ow   + (size_t)i * 128 * 256;

    // 1. in_proj: [M,128]@[512,128]^T -> xa_pre(f2), silu(z)(f3)
    gemm_awt<<<dim3(MROWS / 64, 8), 256, 0, stream>>>(
        cur, wi, f2, f3, MROWS, 512, 128, 1);
    // 2. conv + silu + transpose -> xa_t (f4)
    conv_silu_t<<<dim3(LSEQ / 128, DINNER / 64, BATCH), 256, 0, stream>>>(
        f2, cwi, cbi, f4);
    // 3. x_proj + dt_proj + softplus -> dt_t(f2), Bt(f6), Ct(f7)
    proj_dt<<<dim3(LSEQ / 64, BATCH), 256, 0, stream>>>(
        f4, xpi, dwi, dbi, f2, f6, f7);
    // 4. selective scan (exact sequential, LDS-DMA pipelined) -> y_t (f8)
    scan_k<<<dim3(BATCH * DINNER / 8), 128, 0, stream>>>(
        f2, f4, f6, f7, ali, dpi, f8);
    // 5. y * silu(z), transpose back -> ymul (f4)
    transmul<<<dim3(LSEQ / 128, DINNER / 64, BATCH), 256, 0, stream>>>(
        f8, f3, f4);
    // 6. out_proj: [M,256]@[128,256]^T -> xout
    gemm_awt<<<dim3(MROWS / 64, 2), 256, 0, stream>>>(
        f4, owi, xout, nullptr, MROWS, 128, 256, 0);

    cur = xout;
  }
}

// Round 9
// 1535.611 us; speedup vs baseline: 1.4480x; 1.4480x over previous
//
#include <hip/hip_runtime.h>
#include <cstddef>

#define BATCH   8
#define LSEQ    4096
#define DMODEL  128
#define DINNER  256
#define NSTATE  16
#define NLAYER  4
#define MROWS   (BATCH*LSEQ)   // 32768

__device__ __forceinline__ float silu_f(float v) { return v / (1.f + expf(-v)); }
__device__ __forceinline__ float softplus_f(float v) {
  return v > 20.f ? v : log1pf(expf(v));
}

// v_add_f32_dpp row_shr reduction step: returns the row-shifted value
// (lanes shifted right by K within each 16-lane row, zero-filled).
template <int CTRL>
__device__ __forceinline__ float dpp_shift(float v) {
  int r = __builtin_amdgcn_update_dpp(0, __float_as_int(v), CTRL, 0xF, 0xF, true);
  return __int_as_float(r);
}

// ---------------------------------------------------------------------------
// Generic tiled GEMM: C = A[M,K] @ W[N,K]^T
// mode 0: out0[m*N + n] = c
// mode 1: (N==512) n<256 -> out0[m*256+n] = c (raw xa); n>=256 -> out1 = silu(c)
// ---------------------------------------------------------------------------
__global__ __launch_bounds__(256) void gemm_awt(
    const float* __restrict__ A, const float* __restrict__ W,
    float* __restrict__ out0, float* __restrict__ out1,
    int M, int N, int K, int mode)
{
  __shared__ float As[32][68];
  __shared__ float Bs[32][68];
  const int m0 = blockIdx.x * 64;
  const int n0 = blockIdx.y * 64;
  const int t  = threadIdx.x;
  const int tx = t & 15, ty = t >> 4;
  const int kk_s = t & 31, row_s = t >> 5;

  float acc[4][4] = {};

  for (int k0 = 0; k0 < K; k0 += 32) {
#pragma unroll
    for (int p = 0; p < 8; ++p) {
      int r = row_s + p * 8;
      As[kk_s][r] = A[(size_t)(m0 + r) * K + (k0 + kk_s)];
      Bs[kk_s][r] = W[(size_t)(n0 + r) * K + (k0 + kk_s)];
    }
    __syncthreads();
#pragma unroll
    for (int kk = 0; kk < 32; ++kk) {
      float4 a4 = *(const float4*)&As[kk][ty * 4];
      float4 b4 = *(const float4*)&Bs[kk][tx * 4];
      float av[4] = {a4.x, a4.y, a4.z, a4.w};
      float bv[4] = {b4.x, b4.y, b4.z, b4.w};
#pragma unroll
      for (int i = 0; i < 4; ++i)
#pragma unroll
        for (int j = 0; j < 4; ++j)
          acc[i][j] = fmaf(av[i], bv[j], acc[i][j]);
    }
    __syncthreads();
  }

#pragma unroll
  for (int i = 0; i < 4; ++i) {
    int m = m0 + ty * 4 + i;
    float4 c4 = make_float4(acc[i][0], acc[i][1], acc[i][2], acc[i][3]);
    if (mode == 0) {
      *(float4*)&out0[(size_t)m * N + n0 + tx * 4] = c4;
    } else {
      int n = n0 + tx * 4;
      if (n < 256) {
        *(float4*)&out0[(size_t)m * 256 + n] = c4;
      } else {
        c4.x = silu_f(c4.x); c4.y = silu_f(c4.y);
        c4.z = silu_f(c4.z); c4.w = silu_f(c4.w);
        *(float4*)&out1[(size_t)m * 256 + (n - 256)] = c4;
      }
    }
  }
}

// ---------------------------------------------------------------------------
// Causal depthwise conv (k=4) + bias + silu, with [M,256] -> [B,256,L] transpose
// ---------------------------------------------------------------------------
__global__ __launch_bounds__(256) void conv_silu_t(
    const float* __restrict__ xa_rm,   // [M,256]
    const float* __restrict__ cw,      // [256,4]
    const float* __restrict__ cb,      // [256]
    float* __restrict__ xa_t)          // [B,256,L]
{
  __shared__ float tile[64][133];      // [dd][li], li=0 ~ l0-3
  __shared__ float s_cw[64][4];
  __shared__ float s_cb[64];
  const int b  = blockIdx.z;
  const int d0 = blockIdx.y * 64;
  const int l0 = blockIdx.x * 128;
  const int t  = threadIdx.x;

  if (t < 64) {
    s_cb[t] = cb[d0 + t];
#pragma unroll
    for (int k = 0; k < 4; ++k) s_cw[t][k] = cw[(d0 + t) * 4 + k];
  }
  const int dd_st = t & 63;
  for (int li = t >> 6; li < 131; li += 4) {
    int l = l0 - 3 + li;
    float v = 0.f;
    if (l >= 0) v = xa_rm[((size_t)(b * LSEQ + l)) * 256 + d0 + dd_st];
    tile[dd_st][li] = v;
  }
  __syncthreads();

  for (int idx = t; idx < 64 * 128; idx += 256) {
    int dd = idx >> 7;
    int lc = idx & 127;
    float v = s_cb[dd]
            + tile[dd][lc + 0] * s_cw[dd][0]
            + tile[dd][lc + 1] * s_cw[dd][1]
            + tile[dd][lc + 2] * s_cw[dd][2]
            + tile[dd][lc + 3] * s_cw[dd][3];
    v = silu_f(v);
    xa_t[((size_t)(b * DINNER + d0 + dd)) * LSEQ + l0 + lc] = v;
  }
}

// ---------------------------------------------------------------------------
// Fused x_proj (40x256) + dt_proj (256x8) + softplus.
// Writes dt_t [B,256,L], Bt/Ct [B,16,L]  (state-major, L-contiguous).
// ---------------------------------------------------------------------------
__global__ __launch_bounds__(256) void proj_dt(
    const float* __restrict__ xa_t,    // [B,256,L]
    const float* __restrict__ xp_w,    // [40,256]
    const float* __restrict__ dtp_w,   // [256,8]
    const float* __restrict__ dtp_b,   // [256]
    float* __restrict__ dt_t,          // [B,256,L]
    float* __restrict__ Bt,            // [B,16,L]
    float* __restrict__ Ct)            // [B,16,L]
{
  __shared__ float s_xpc[40][68];
  __shared__ float s_dtw[256 * 8];
  __shared__ float s_dtb[256];
  __shared__ float s_xa[64][68];
  __shared__ float s_proj[64][44];
  const int b  = blockIdx.y;
  const int l0 = blockIdx.x * 64;
  const int t  = threadIdx.x;

  for (int i = t; i < 256 * 8; i += 256) s_dtw[i] = dtp_w[i];
  s_dtb[t] = dtp_b[t];

  const int ll_st  = t & 63;
  const int kk0_st = t >> 6;
  const int kk_w   = t & 63;
  const int nb_w   = t >> 6;
  const int lA = t & 31;
  const int g  = t >> 5;

  float acc0[5] = {}, acc1[5] = {};

  for (int kc = 0; kc < 256; kc += 64) {
    __syncthreads();
#pragma unroll
    for (int p = 0; p < 16; ++p) {
      int kk = kk0_st + p * 4;
      s_xa[ll_st][kk] =
          xa_t[((size_t)(b * DINNER + kc + kk)) * LSEQ + l0 + ll_st];
    }
#pragma unroll
    for (int p = 0; p < 10; ++p) {
      int n = nb_w + p * 4;
      s_xpc[n][kk_w] = xp_w[n * 256 + kc + kk_w];
    }
    __syncthreads();
#pragma unroll
    for (int kk = 0; kk < 64; kk += 4) {
      float4 a0 = *(const float4*)&s_xa[lA][kk];
      float4 a1 = *(const float4*)&s_xa[lA + 32][kk];
#pragma unroll
      for (int j = 0; j < 5; ++j) {
        float4 w4 = *(const float4*)&s_xpc[g * 5 + j][kk];
        acc0[j] = fmaf(a0.x, w4.x, fmaf(a0.y, w4.y,
                  fmaf(a0.z, w4.z, fmaf(a0.w, w4.w, acc0[j]))));
        acc1[j] = fmaf(a1.x, w4.x, fmaf(a1.y, w4.y,
                  fmaf(a1.z, w4.z, fmaf(a1.w, w4.w, acc1[j]))));
      }
    }
  }
  __syncthreads();
#pragma unroll
  for (int j = 0; j < 5; ++j) {
    s_proj[lA][g * 5 + j]      = acc0[j];
    s_proj[lA + 32][g * 5 + j] = acc1[j];
  }
  __syncthreads();

  const int ll = t & 63;
  const int dgroup = t >> 6;
  float4 p0 = *(const float4*)&s_proj[ll][0];
  float4 p1 = *(const float4*)&s_proj[ll][4];
  for (int j = 0; j < 64; ++j) {
    int dout = dgroup * 64 + j;
    float4 w0 = *(const float4*)&s_dtw[dout * 8];
    float4 w1 = *(const float4*)&s_dtw[dout * 8 + 4];
    float v = s_dtb[dout]
            + p0.x * w0.x + p0.y * w0.y + p0.z * w0.z + p0.w * w0.w
            + p1.x * w1.x + p1.y * w1.y + p1.z * w1.z + p1.w * w1.w;
    dt_t[((size_t)(b * DINNER + dout)) * LSEQ + l0 + ll] = softplus_f(v);
  }
  // Bt/Ct: [B,16,L] — 64 consecutive l-addresses per instruction (coalesced)
  if (t < 64) {
#pragma unroll
    for (int nn = 0; nn < 16; ++nn)
      Bt[((size_t)(b * NSTATE + nn)) * LSEQ + l0 + t] = s_proj[t][8 + nn];
  } else if (t < 128) {
    int lw = t - 64;
#pragma unroll
    for (int nn = 0; nn < 16; ++nn)
      Ct[((size_t)(b * NSTATE + nn)) * LSEQ + l0 + lw] = s_proj[lw][24 + nn];
  }
}

// ---------------------------------------------------------------------------
// Selective scan — exact sequential recurrence (same fmaf chain order as
// R0..R8). Two per-step cost cuts vs R7 (justified because the harness ref
// is f64 — faithful fp32 math suffices, bit-identity to libm not required):
//  1. __expf (native v_exp, ~2 inst) replaces libm expf (~18 inst).
//  2. 16-lane y-reduction via v_add_f32_dpp row_shr 8/4/2/1 (VALU pipe,
//     sum lands at lane n==0) replaces 4 dependent ds_swizzle levels.
// Register prefetch ring (R6 structure, fences removed — measured no-op).
// 16 lanes (one per state n) per (b,d) channel; 4 channels/wave.
// grid: BATCH * DINNER/4 = 512 blocks of 64 threads.
// ---------------------------------------------------------------------------
__global__ __launch_bounds__(64) void scan_k(
    const float* __restrict__ dt_t, const float* __restrict__ u_t,
    const float* __restrict__ Bt,   const float* __restrict__ Ct,
    const float* __restrict__ A_log, const float* __restrict__ Dp,
    float* __restrict__ y_t)
{
  const int blk = blockIdx.x;
  const int b   = blk >> 6;
  const int d0  = (blk & 63) * 4;
  const int lane = threadIdx.x;
  const int g = lane >> 4;
  const int n = lane & 15;
  const int d = d0 + g;

  const float Aa = -expf(A_log[d * NSTATE + n]);   // once; keep libm here
  const float Dv = Dp[d];
  const float4* dtp = (const float4*)(dt_t + ((size_t)(b * DINNER + d)) * LSEQ);
  const float4* up  = (const float4*)(u_t  + ((size_t)(b * DINNER + d)) * LSEQ);
  const float4* Bp  = (const float4*)(Bt + ((size_t)(b * NSTATE + n)) * LSEQ);
  const float4* Cp  = (const float4*)(Ct + ((size_t)(b * NSTATE + n)) * LSEQ);
  float4* yp = (float4*)(y_t + ((size_t)(b * DINNER + d)) * LSEQ);

  const int NG = LSEQ / 8;             // 512 groups of 8 steps
  float4 Rd[4][2], Ru[4][2], Rb[4][2], Rc[4][2];   // 4-deep ring
  float h = 0.f;

#define LOAD_GRP(s, grp) do {                                            \
    int _gg = (grp) < NG ? (grp) : NG - 1;                               \
    int _base = _gg * 2;                                                 \
    _Pragma("unroll")                                                    \
    for (int q = 0; q < 2; ++q) {                                        \
      Rd[s][q] = dtp[_base + q];  Ru[s][q] = up[_base + q];              \
      Rb[s][q] = Bp[_base + q];   Rc[s][q] = Cp[_base + q];              \
    }                                                                    \
  } while (0)

#define COMP_GRP(s, grp) do {                                            \
    float p[8], us8[8];                                                  \
    _Pragma("unroll")                                                    \
    for (int q = 0; q < 2; ++q) {                                        \
      float dts[4] = {Rd[s][q].x, Rd[s][q].y, Rd[s][q].z, Rd[s][q].w};   \
      float uq[4]  = {Ru[s][q].x, Ru[s][q].y, Ru[s][q].z, Ru[s][q].w};   \
      float bv[4]  = {Rb[s][q].x, Rb[s][q].y, Rb[s][q].z, Rb[s][q].w};   \
      float cv[4]  = {Rc[s][q].x, Rc[s][q].y, Rc[s][q].z, Rc[s][q].w};   \
      _Pragma("unroll")                                                  \
      for (int st = 0; st < 4; ++st) {                                   \
        int i = q * 4 + st;                                              \
        float a = __expf(dts[st] * Aa);                                  \
        h = fmaf(a, h, (dts[st] * uq[st]) * bv[st]);                     \
        p[i] = h * cv[st];                                               \
        us8[i] = uq[st];                                                 \
      }                                                                  \
    }                                                                    \
    /* 16-lane row reduction on VALU via DPP; sum lands at lane n==0 */  \
    _Pragma("unroll")                                                    \
    for (int i = 0; i < 8; ++i) p[i] += dpp_shift<0x118>(p[i]);          \
    _Pragma("unroll")                                                    \
    for (int i = 0; i < 8; ++i) p[i] += dpp_shift<0x114>(p[i]);          \
    _Pragma("unroll")                                                    \
    for (int i = 0; i < 8; ++i) p[i] += dpp_shift<0x112>(p[i]);          \
    _Pragma("unroll")                                                    \
    for (int i = 0; i < 8; ++i) p[i] += dpp_shift<0x111>(p[i]);          \
    if (n == 0) {                                                        \
      _Pragma("unroll")                                                  \
      for (int q = 0; q < 2; ++q)                                        \
        yp[(grp) * 2 + q] = make_float4(                                 \
            fmaf(us8[q*4+0], Dv, p[q*4+0]),                              \
            fmaf(us8[q*4+1], Dv, p[q*4+1]),                              \
            fmaf(us8[q*4+2], Dv, p[q*4+2]),                              \
            fmaf(us8[q*4+3], Dv, p[q*4+3]));                             \
    }                                                                    \
  } while (0)

  LOAD_GRP(0, 0);
  LOAD_GRP(1, 1);
  LOAD_GRP(2, 2);
  for (int it = 0; it < NG; it += 4) {
    LOAD_GRP(3, it + 3);
    COMP_GRP(0, it);
    LOAD_GRP(0, it + 4);
    COMP_GRP(1, it + 1);
    LOAD_GRP(1, it + 5);
    COMP_GRP(2, it + 2);
    LOAD_GRP(2, it + 6);
    COMP_GRP(3, it + 3);
  }
#undef LOAD_GRP
#undef COMP_GRP
}

// ---------------------------------------------------------------------------
// ymul[m,d] = y_t[b,d,l] * zs[m,d]   ([B,256,L] -> [M,256] transpose, fused mul)
// ---------------------------------------------------------------------------
__global__ __launch_bounds__(256) void transmul(
    const float* __restrict__ y_t, const float* __restrict__ zs,
    float* __restrict__ outA)
{
  __shared__ float tile[64][129];
  const int b  = blockIdx.z;
  const int d0 = blockIdx.y * 64;
  const int l0 = blockIdx.x * 128;
  const int t  = threadIdx.x;
  const int lc_st = t & 127;
  for (int dd = t >> 7; dd < 64; dd += 2)
    tile[dd][lc_st] = y_t[((size_t)(b * DINNER + d0 + dd)) * LSEQ + l0 + lc_st];
  __syncthreads();
  for (int idx = t; idx < 64 * 128; idx += 256) {
    int dd = idx & 63, lc = idx >> 6;
    size_t addr = ((size_t)(b * LSEQ) + l0 + lc) * DINNER + d0 + dd;
    outA[addr] = tile[dd][lc] * zs[addr];
  }
}

// ---------------------------------------------------------------------------
extern "C" void kernel_launch(void* const* d_in, const int* in_sizes, int n_in,
                              void* d_out, int out_size, void* d_ws, size_t ws_size,
                              hipStream_t stream) {
  const float* x_in  = (const float*)d_in[0];
  const float* w_in  = (const float*)d_in[1];   // [4,512,128]
  const float* cw    = (const float*)d_in[2];   // [4,256,4]
  const float* cb    = (const float*)d_in[3];   // [4,256]
  const float* xpw   = (const float*)d_in[4];   // [4,40,256]
  const float* dtw   = (const float*)d_in[5];   // [4,256,8]
  const float* dtb   = (const float*)d_in[6];   // [4,256]
  const float* alog  = (const float*)d_in[7];   // [4,256,16]
  const float* Dp    = (const float*)d_in[8];   // [4,256]
  const float* ow    = (const float*)d_in[9];   // [4,128,256]
  float* out = (float*)d_out;

  const size_t M = MROWS;
  float* f0 = (float*)d_ws;            // x ping  [M,128]
  float* f1 = f0 + M * 128;            // x pong  [M,128]
  float* f2 = f1 + M * 128;            // xa_pre -> dt_t [B,256,L]
  float* f3 = f2 + M * 256;            // zs = silu(z) [M,256]
  float* f4 = f3 + M * 256;            // xa_t [B,256,L] -> later ymul [M,256]
  float* f6 = f4 + M * 256;            // Bt [B,16,L]
  float* f7 = f6 + M * 16;             // Ct [B,16,L]
  float* f8 = f7 + M * 16;             // y_t [B,256,L]

  const float* cur = x_in;
  for (int i = 0; i < NLAYER; ++i) {
    float* xout = (i == NLAYER - 1) ? out : ((i % 2 == 0) ? f0 : f1);
    const float* wi  = w_in + (size_t)i * 512 * 128;
    const float* cwi = cw   + (size_t)i * 256 * 4;
    const float* cbi = cb   + (size_t)i * 256;
    const float* xpi = xpw  + (size_t)i * 40 * 256;
    const float* dwi = dtw  + (size_t)i * 256 * 8;
    const float* dbi = dtb  + (size_t)i * 256;
    const float* ali = alog + (size_t)i * 256 * 16;
    const float* dpi = Dp   + (size_t)i * 256;
    const float* owi = ow   + (size_t)i * 128 * 256;

    // 1. in_proj: [M,128]@[512,128]^T -> xa_pre(f2), silu(z)(f3)
    gemm_awt<<<dim3(MROWS / 64, 8), 256, 0, stream>>>(
        cur, wi, f2, f3, MROWS, 512, 128, 1);
    // 2. conv + silu + transpose -> xa_t (f4)
    conv_silu_t<<<dim3(LSEQ / 128, DINNER / 64, BATCH), 256, 0, stream>>>(
        f2, cwi, cbi, f4);
    // 3. x_proj + dt_proj + softplus -> dt_t(f2), Bt(f6), Ct(f7)
    proj_dt<<<dim3(LSEQ / 64, BATCH), 256, 0, stream>>>(
        f4, xpi, dwi, dbi, f2, f6, f7);
    // 4. selective scan (exact sequential, __expf + DPP reduce) -> y_t (f8)
    scan_k<<<dim3(BATCH * DINNER / 4), 64, 0, stream>>>(
        f2, f4, f6, f7, ali, dpi, f8);
    // 5. y * silu(z), transpose back -> ymul (f4)
    transmul<<<dim3(LSEQ / 128, DINNER / 64, BATCH), 256, 0, stream>>>(
        f8, f3, f4);
    // 6. out_proj: [M,256]@[128,256]^T -> xout
    gemm_awt<<<dim3(MROWS / 64, 2), 256, 0, stream>>>(
        f4, owi, xout, nullptr, MROWS, 128, 256, 0);

    cur = xout;
  }
}

// Round 13
// 1506.471 us; speedup vs baseline: 1.4760x; 1.0193x over previous
//
#include <hip/hip_runtime.h>
#include <cstddef>

#define BATCH   8
#define LSEQ    4096
#define DMODEL  128
#define DINNER  256
#define NSTATE  16
#define NLAYER  4
#define MROWS   (BATCH*LSEQ)   // 32768

__device__ __forceinline__ float silu_f(float v) { return v / (1.f + expf(-v)); }
__device__ __forceinline__ float softplus_f(float v) {
  return v > 20.f ? v : log1pf(expf(v));
}

// v_add_f32_dpp row_shr reduction step
template <int CTRL>
__device__ __forceinline__ float dpp_shift(float v) {
  int r = __builtin_amdgcn_update_dpp(0, __float_as_int(v), CTRL, 0xF, 0xF, true);
  return __int_as_float(r);
}

// ---------------------------------------------------------------------------
// Generic tiled GEMM: C = A[M,K] @ W[N,K]^T
// mode 0: out0[m*N + n] = c
// mode 1: (N==512) n<256 -> out0[m*256+n] = c (raw xa); n>=256 -> out1 = silu(c)
// ---------------------------------------------------------------------------
__global__ __launch_bounds__(256) void gemm_awt(
    const float* __restrict__ A, const float* __restrict__ W,
    float* __restrict__ out0, float* __restrict__ out1,
    int M, int N, int K, int mode)
{
  __shared__ float As[32][68];
  __shared__ float Bs[32][68];
  const int m0 = blockIdx.x * 64;
  const int n0 = blockIdx.y * 64;
  const int t  = threadIdx.x;
  const int tx = t & 15, ty = t >> 4;
  const int kk_s = t & 31, row_s = t >> 5;

  float acc[4][4] = {};

  for (int k0 = 0; k0 < K; k0 += 32) {
#pragma unroll
    for (int p = 0; p < 8; ++p) {
      int r = row_s + p * 8;
      As[kk_s][r] = A[(size_t)(m0 + r) * K + (k0 + kk_s)];
      Bs[kk_s][r] = W[(size_t)(n0 + r) * K + (k0 + kk_s)];
    }
    __syncthreads();
#pragma unroll
    for (int kk = 0; kk < 32; ++kk) {
      float4 a4 = *(const float4*)&As[kk][ty * 4];
      float4 b4 = *(const float4*)&Bs[kk][tx * 4];
      float av[4] = {a4.x, a4.y, a4.z, a4.w};
      float bv[4] = {b4.x, b4.y, b4.z, b4.w};
#pragma unroll
      for (int i = 0; i < 4; ++i)
#pragma unroll
        for (int j = 0; j < 4; ++j)
          acc[i][j] = fmaf(av[i], bv[j], acc[i][j]);
    }
    __syncthreads();
  }

#pragma unroll
  for (int i = 0; i < 4; ++i) {
    int m = m0 + ty * 4 + i;
    float4 c4 = make_float4(acc[i][0], acc[i][1], acc[i][2], acc[i][3]);
    if (mode == 0) {
      *(float4*)&out0[(size_t)m * N + n0 + tx * 4] = c4;
    } else {
      int n = n0 + tx * 4;
      if (n < 256) {
        *(float4*)&out0[(size_t)m * 256 + n] = c4;
      } else {
        c4.x = silu_f(c4.x); c4.y = silu_f(c4.y);
        c4.z = silu_f(c4.z); c4.w = silu_f(c4.w);
        *(float4*)&out1[(size_t)m * 256 + (n - 256)] = c4;
      }
    }
  }
}

// ---------------------------------------------------------------------------
// out_proj GEMM with fused y*silu(z) and y_t-transpose read (transmul gone):
// out[m,n] = sum_k ( y_t[b, k, l] * zs[m, k] ) * W[n, k]
// where m = b*LSEQ + l. Per 64-row tile all m share one b (LSEQ % 64 == 0),
// so y_t is K-major within the tile: staged m-contiguous (coalesced), then
// multiplied into the zs tile in LDS — the fp32 product is bit-identical to
// what transmul wrote, so the result matches R9 exactly.
// ---------------------------------------------------------------------------
__global__ __launch_bounds__(256) void gemm_yz(
    const float* __restrict__ yT,      // [B,256,L]
    const float* __restrict__ zs,      // [M,256]
    const float* __restrict__ W,       // [128,256]
    float* __restrict__ out0)          // [M,128]
{
  __shared__ float As[32][68];
  __shared__ float Bs[32][68];
  const int m0 = blockIdx.x * 64;
  const int n0 = blockIdx.y * 64;
  const int b  = m0 >> 12;             // m0 / LSEQ
  const int l0 = m0 & (LSEQ - 1);
  const int t  = threadIdx.x;
  const int tx = t & 15, ty = t >> 4;
  const int kk_s = t & 31, row_s = t >> 5;
  const int mm = t & 63, kq = t >> 6;  // y staging / RMW mapping

  float acc[4][4] = {};

  for (int k0 = 0; k0 < 256; k0 += 32) {
#pragma unroll
    for (int p = 0; p < 8; ++p) {
      int r = row_s + p * 8;
      As[kk_s][r] = zs[(size_t)(m0 + r) * 256 + (k0 + kk_s)];
      Bs[kk_s][r] = W[(size_t)(n0 + r) * 256 + (k0 + kk_s)];
    }
    __syncthreads();
    // As[k][mm] *= y_t[b, k0+k, l0+mm]  (global read coalesced over mm)
#pragma unroll
    for (int p = 0; p < 8; ++p) {
      int k = kq + p * 4;
      As[k][mm] *= yT[((size_t)(b * DINNER + k0 + k)) * LSEQ + l0 + mm];
    }
    __syncthreads();
#pragma unroll
    for (int kk = 0; kk < 32; ++kk) {
      float4 a4 = *(const float4*)&As[kk][ty * 4];
      float4 b4 = *(const float4*)&Bs[kk][tx * 4];
      float av[4] = {a4.x, a4.y, a4.z, a4.w};
      float bv[4] = {b4.x, b4.y, b4.z, b4.w};
#pragma unroll
      for (int i = 0; i < 4; ++i)
#pragma unroll
        for (int j = 0; j < 4; ++j)
          acc[i][j] = fmaf(av[i], bv[j], acc[i][j]);
    }
    __syncthreads();
  }

#pragma unroll
  for (int i = 0; i < 4; ++i) {
    int m = m0 + ty * 4 + i;
    *(float4*)&out0[(size_t)m * DMODEL + n0 + tx * 4] =
        make_float4(acc[i][0], acc[i][1], acc[i][2], acc[i][3]);
  }
}

// ---------------------------------------------------------------------------
// Causal depthwise conv (k=4) + bias + silu, with [M,256] -> [B,256,L] transpose
// ---------------------------------------------------------------------------
__global__ __launch_bounds__(256) void conv_silu_t(
    const float* __restrict__ xa_rm,   // [M,256]
    const float* __restrict__ cw,      // [256,4]
    const float* __restrict__ cb,      // [256]
    float* __restrict__ xa_t)          // [B,256,L]
{
  __shared__ float tile[64][133];      // [dd][li], li=0 ~ l0-3
  __shared__ float s_cw[64][4];
  __shared__ float s_cb[64];
  const int b  = blockIdx.z;
  const int d0 = blockIdx.y * 64;
  const int l0 = blockIdx.x * 128;
  const int t  = threadIdx.x;

  if (t < 64) {
    s_cb[t] = cb[d0 + t];
#pragma unroll
    for (int k = 0; k < 4; ++k) s_cw[t][k] = cw[(d0 + t) * 4 + k];
  }
  const int dd_st = t & 63;
  for (int li = t >> 6; li < 131; li += 4) {
    int l = l0 - 3 + li;
    float v = 0.f;
    if (l >= 0) v = xa_rm[((size_t)(b * LSEQ + l)) * 256 + d0 + dd_st];
    tile[dd_st][li] = v;
  }
  __syncthreads();

  for (int idx = t; idx < 64 * 128; idx += 256) {
    int dd = idx >> 7;
    int lc = idx & 127;
    float v = s_cb[dd]
            + tile[dd][lc + 0] * s_cw[dd][0]
            + tile[dd][lc + 1] * s_cw[dd][1]
            + tile[dd][lc + 2] * s_cw[dd][2]
            + tile[dd][lc + 3] * s_cw[dd][3];
    v = silu_f(v);
    xa_t[((size_t)(b * DINNER + d0 + dd)) * LSEQ + l0 + lc] = v;
  }
}

// ---------------------------------------------------------------------------
// Fused x_proj (40x256) + dt_proj (256x8) + softplus.
// Writes dt_t [B,256,L], Bt/Ct [B,16,L]  (state-major, L-contiguous).
// ---------------------------------------------------------------------------
__global__ __launch_bounds__(256) void proj_dt(
    const float* __restrict__ xa_t,    // [B,256,L]
    const float* __restrict__ xp_w,    // [40,256]
    const float* __restrict__ dtp_w,   // [256,8]
    const float* __restrict__ dtp_b,   // [256]
    float* __restrict__ dt_t,          // [B,256,L]
    float* __restrict__ Bt,            // [B,16,L]
    float* __restrict__ Ct)            // [B,16,L]
{
  __shared__ float s_xpc[40][68];
  __shared__ float s_dtw[256 * 8];
  __shared__ float s_dtb[256];
  __shared__ float s_xa[64][68];
  __shared__ float s_proj[64][44];
  const int b  = blockIdx.y;
  const int l0 = blockIdx.x * 64;
  const int t  = threadIdx.x;

  for (int i = t; i < 256 * 8; i += 256) s_dtw[i] = dtp_w[i];
  s_dtb[t] = dtp_b[t];

  const int ll_st  = t & 63;
  const int kk0_st = t >> 6;
  const int kk_w   = t & 63;
  const int nb_w   = t >> 6;
  const int lA = t & 31;
  const int g  = t >> 5;

  float acc0[5] = {}, acc1[5] = {};

  for (int kc = 0; kc < 256; kc += 64) {
    __syncthreads();
#pragma unroll
    for (int p = 0; p < 16; ++p) {
      int kk = kk0_st + p * 4;
      s_xa[ll_st][kk] =
          xa_t[((size_t)(b * DINNER + kc + kk)) * LSEQ + l0 + ll_st];
    }
#pragma unroll
    for (int p = 0; p < 10; ++p) {
      int n = nb_w + p * 4;
      s_xpc[n][kk_w] = xp_w[n * 256 + kc + kk_w];
    }
    __syncthreads();
#pragma unroll
    for (int kk = 0; kk < 64; kk += 4) {
      float4 a0 = *(const float4*)&s_xa[lA][kk];
      float4 a1 = *(const float4*)&s_xa[lA + 32][kk];
#pragma unroll
      for (int j = 0; j < 5; ++j) {
        float4 w4 = *(const float4*)&s_xpc[g * 5 + j][kk];
        acc0[j] = fmaf(a0.x, w4.x, fmaf(a0.y, w4.y,
                  fmaf(a0.z, w4.z, fmaf(a0.w, w4.w, acc0[j]))));
        acc1[j] = fmaf(a1.x, w4.x, fmaf(a1.y, w4.y,
                  fmaf(a1.z, w4.z, fmaf(a1.w, w4.w, acc1[j]))));
      }
    }
  }
  __syncthreads();
#pragma unroll
  for (int j = 0; j < 5; ++j) {
    s_proj[lA][g * 5 + j]      = acc0[j];
    s_proj[lA + 32][g * 5 + j] = acc1[j];
  }
  __syncthreads();

  const int ll = t & 63;
  const int dgroup = t >> 6;
  float4 p0 = *(const float4*)&s_proj[ll][0];
  float4 p1 = *(const float4*)&s_proj[ll][4];
  for (int j = 0; j < 64; ++j) {
    int dout = dgroup * 64 + j;
    float4 w0 = *(const float4*)&s_dtw[dout * 8];
    float4 w1 = *(const float4*)&s_dtw[dout * 8 + 4];
    float v = s_dtb[dout]
            + p0.x * w0.x + p0.y * w0.y + p0.z * w0.z + p0.w * w0.w
            + p1.x * w1.x + p1.y * w1.y + p1.z * w1.z + p1.w * w1.w;
    dt_t[((size_t)(b * DINNER + dout)) * LSEQ + l0 + ll] = softplus_f(v);
  }
  // Bt/Ct: [B,16,L] — 64 consecutive l-addresses per instruction (coalesced)
  if (t < 64) {
#pragma unroll
    for (int nn = 0; nn < 16; ++nn)
      Bt[((size_t)(b * NSTATE + nn)) * LSEQ + l0 + t] = s_proj[t][8 + nn];
  } else if (t < 128) {
    int lw = t - 64;
#pragma unroll
    for (int nn = 0; nn < 16; ++nn)
      Ct[((size_t)(b * NSTATE + nn)) * LSEQ + l0 + lw] = s_proj[lw][24 + nn];
  }
}

// ---------------------------------------------------------------------------
// Selective scan — EXACT R9 version (known-good: 158 µs/layer, absmax
// 1.746e-10). Sequential recurrence; __expf; DPP row_shr reduction.
// Deep register prefetch was tried 5 ways (R6 ring, R7 sched_barrier,
// R9 ring, R11/R12 inline-asm loads) — the compiler either sinks the loads
// (depth collapses to ~1) or RA inserts copies that race the in-flight asm
// loads (crashes). 158 µs is this structure's plateau; do not re-attempt
// register prefetch via source-level tricks.
// 16 lanes (one per state n) per (b,d) channel; 4 channels/wave.
// grid: BATCH * DINNER/4 = 512 blocks of 64 threads.
// ---------------------------------------------------------------------------
__global__ __launch_bounds__(64) void scan_k(
    const float* __restrict__ dt_t, const float* __restrict__ u_t,
    const float* __restrict__ Bt,   const float* __restrict__ Ct,
    const float* __restrict__ A_log, const float* __restrict__ Dp,
    float* __restrict__ y_t)
{
  const int blk = blockIdx.x;
  const int b   = blk >> 6;
  const int d0  = (blk & 63) * 4;
  const int lane = threadIdx.x;
  const int g = lane >> 4;
  const int n = lane & 15;
  const int d = d0 + g;

  const float Aa = -expf(A_log[d * NSTATE + n]);   // once; keep libm here
  const float Dv = Dp[d];
  const float4* dtp = (const float4*)(dt_t + ((size_t)(b * DINNER + d)) * LSEQ);
  const float4* up  = (const float4*)(u_t  + ((size_t)(b * DINNER + d)) * LSEQ);
  const float4* Bp  = (const float4*)(Bt + ((size_t)(b * NSTATE + n)) * LSEQ);
  const float4* Cp  = (const float4*)(Ct + ((size_t)(b * NSTATE + n)) * LSEQ);
  float4* yp = (float4*)(y_t + ((size_t)(b * DINNER + d)) * LSEQ);

  const int NG = LSEQ / 8;             // 512 groups of 8 steps
  float4 Rd[4][2], Ru[4][2], Rb[4][2], Rc[4][2];   // 4-deep ring
  float h = 0.f;

#define LOAD_GRP(s, grp) do {                                            \
    int _gg = (grp) < NG ? (grp) : NG - 1;                               \
    int _base = _gg * 2;                                                 \
    _Pragma("unroll")                                                    \
    for (int q = 0; q < 2; ++q) {                                        \
      Rd[s][q] = dtp[_base + q];  Ru[s][q] = up[_base + q];              \
      Rb[s][q] = Bp[_base + q];   Rc[s][q] = Cp[_base + q];              \
    }                                                                    \
  } while (0)

#define COMP_GRP(s, grp) do {                                            \
    float p[8], us8[8];                                                  \
    _Pragma("unroll")                                                    \
    for (int q = 0; q < 2; ++q) {                                        \
      float dts[4] = {Rd[s][q].x, Rd[s][q].y, Rd[s][q].z, Rd[s][q].w};   \
      float uq[4]  = {Ru[s][q].x, Ru[s][q].y, Ru[s][q].z, Ru[s][q].w};   \
      float bv[4]  = {Rb[s][q].x, Rb[s][q].y, Rb[s][q].z, Rb[s][q].w};   \
      float cv[4]  = {Rc[s][q].x, Rc[s][q].y, Rc[s][q].z, Rc[s][q].w};   \
      _Pragma("unroll")                                                  \
      for (int st = 0; st < 4; ++st) {                                   \
        int i = q * 4 + st;                                              \
        float a = __expf(dts[st] * Aa);                                  \
        h = fmaf(a, h, (dts[st] * uq[st]) * bv[st]);                     \
        p[i] = h * cv[st];                                               \
        us8[i] = uq[st];                                                 \
      }                                                                  \
    }                                                                    \
    /* 16-lane row reduction on VALU via DPP; sum lands at lane n==0 */  \
    _Pragma("unroll")                                                    \
    for (int i = 0; i < 8; ++i) p[i] += dpp_shift<0x118>(p[i]);          \
    _Pragma("unroll")                                                    \
    for (int i = 0; i < 8; ++i) p[i] += dpp_shift<0x114>(p[i]);          \
    _Pragma("unroll")                                                    \
    for (int i = 0; i < 8; ++i) p[i] += dpp_shift<0x112>(p[i]);          \
    _Pragma("unroll")                                                    \
    for (int i = 0; i < 8; ++i) p[i] += dpp_shift<0x111>(p[i]);          \
    if (n == 0) {                                                        \
      _Pragma("unroll")                                                  \
      for (int q = 0; q < 2; ++q)                                        \
        yp[(grp) * 2 + q] = make_float4(                                 \
            fmaf(us8[q*4+0], Dv, p[q*4+0]),                              \
            fmaf(us8[q*4+1], Dv, p[q*4+1]),                              \
            fmaf(us8[q*4+2], Dv, p[q*4+2]),                              \
            fmaf(us8[q*4+3], Dv, p[q*4+3]));                             \
    }                                                                    \
  } while (0)

  LOAD_GRP(0, 0);
  LOAD_GRP(1, 1);
  LOAD_GRP(2, 2);
  for (int it = 0; it < NG; it += 4) {
    LOAD_GRP(3, it + 3);
    COMP_GRP(0, it);
    LOAD_GRP(0, it + 4);
    COMP_GRP(1, it + 1);
    LOAD_GRP(1, it + 5);
    COMP_GRP(2, it + 2);
    LOAD_GRP(2, it + 6);
    COMP_GRP(3, it + 3);
  }
#undef LOAD_GRP
#undef COMP_GRP
}

// ---------------------------------------------------------------------------
extern "C" void kernel_launch(void* const* d_in, const int* in_sizes, int n_in,
                              void* d_out, int out_size, void* d_ws, size_t ws_size,
                              hipStream_t stream) {
  const float* x_in  = (const float*)d_in[0];
  const float* w_in  = (const float*)d_in[1];   // [4,512,128]
  const float* cw    = (const float*)d_in[2];   // [4,256,4]
  const float* cb    = (const float*)d_in[3];   // [4,256]
  const float* xpw   = (const float*)d_in[4];   // [4,40,256]
  const float* dtw   = (const float*)d_in[5];   // [4,256,8]
  const float* dtb   = (const float*)d_in[6];   // [4,256]
  const float* alog  = (const float*)d_in[7];   // [4,256,16]
  const float* Dp    = (const float*)d_in[8];   // [4,256]
  const float* ow    = (const float*)d_in[9];   // [4,128,256]
  float* out = (float*)d_out;

  const size_t M = MROWS;
  float* f0 = (float*)d_ws;            // x ping  [M,128]
  float* f1 = f0 + M * 128;            // x pong  [M,128]
  float* f2 = f1 + M * 128;            // xa_pre -> dt_t [B,256,L]
  float* f3 = f2 + M * 256;            // zs = silu(z) [M,256]
  float* f4 = f3 + M * 256;            // xa_t [B,256,L]
  float* f6 = f4 + M * 256;            // Bt [B,16,L]
  float* f7 = f6 + M * 16;             // Ct [B,16,L]
  float* f8 = f7 + M * 16;             // y_t [B,256,L]

  const float* cur = x_in;
  for (int i = 0; i < NLAYER; ++i) {
    float* xout = (i == NLAYER - 1) ? out : ((i % 2 == 0) ? f0 : f1);
    const float* wi  = w_in + (size_t)i * 512 * 128;
    const float* cwi = cw   + (size_t)i * 256 * 4;
    const float* cbi = cb   + (size_t)i * 256;
    const float* xpi = xpw  + (size_t)i * 40 * 256;
    const float* dwi = dtw  + (size_t)i * 256 * 8;
    const float* dbi = dtb  + (size_t)i * 256;
    const float* ali = alog + (size_t)i * 256 * 16;
    const float* dpi = Dp   + (size_t)i * 256;
    const float* owi = ow   + (size_t)i * 128 * 256;

    // 1. in_proj: [M,128]@[512,128]^T -> xa_pre(f2), silu(z)(f3)
    gemm_awt<<<dim3(MROWS / 64, 8), 256, 0, stream>>>(
        cur, wi, f2, f3, MROWS, 512, 128, 1);
    // 2. conv + silu + transpose -> xa_t (f4)
    conv_silu_t<<<dim3(LSEQ / 128, DINNER / 64, BATCH), 256, 0, stream>>>(
        f2, cwi, cbi, f4);
    // 3. x_proj + dt_proj + softplus -> dt_t(f2), Bt(f6), Ct(f7)
    proj_dt<<<dim3(LSEQ / 64, BATCH), 256, 0, stream>>>(
        f4, xpi, dwi, dbi, f2, f6, f7);
    // 4. selective scan (exact R9) -> y_t (f8)
    scan_k<<<dim3(BATCH * DINNER / 4), 64, 0, stream>>>(
        f2, f4, f6, f7, ali, dpi, f8);
    // 5. out_proj with fused y*silu(z) + transpose read -> xout
    gemm_yz<<<dim3(MROWS / 64, 2), 256, 0, stream>>>(
        f8, f3, owi, xout);

    cur = xout;
  }
}

// Round 14
// 1430.061 us; speedup vs baseline: 1.5548x; 1.0534x over previous
//
#include <hip/hip_runtime.h>
#include <cstddef>

#define BATCH   8
#define LSEQ    4096
#define DMODEL  128
#define DINNER  256
#define NSTATE  16
#define NLAYER  4
#define MROWS   (BATCH*LSEQ)   // 32768

__device__ __forceinline__ float silu_f(float v) { return v / (1.f + expf(-v)); }
__device__ __forceinline__ float softplus_f(float v) {
  return v > 20.f ? v : log1pf(expf(v));
}

// v_add_f32_dpp row_shr reduction step
template <int CTRL>
__device__ __forceinline__ float dpp_shift(float v) {
  int r = __builtin_amdgcn_update_dpp(0, __float_as_int(v), CTRL, 0xF, 0xF, true);
  return __int_as_float(r);
}

// ---------------------------------------------------------------------------
// in_proj GEMM: [M,128] @ [512,128]^T, 128x128 tile, 8x8 per thread.
// 2 FLOP per LDS byte (vs 1 for the old 64x64/4x4) — the old kernel was
// LDS-throughput-bound (~4.2 GB inner-loop reads @ ~52 TB/s). Fragment reads
// split as two 64-wide halves (tx*4 / 64+tx*4) -> every ds_read_b128 is
// <=2-way bank-aliased (free, m136). Accumulation per output stays one fmaf
// per k in ascending k -> bit-identical to the previous kernel.
// n0 < 256 -> xa raw; n0 >= 256 -> silu -> zs.
// ---------------------------------------------------------------------------
__global__ __launch_bounds__(256) void gemm_in(
    const float* __restrict__ A,       // [M,128]
    const float* __restrict__ W,       // [512,128]
    float* __restrict__ xa,            // [M,256]
    float* __restrict__ zs)            // [M,256]
{
  __shared__ float As[32][132];
  __shared__ float Bs[32][132];
  const int m0 = blockIdx.x * 128;
  const int n0 = blockIdx.y * 128;
  const int t  = threadIdx.x;
  const int tx = t & 15, ty = t >> 4;
  const int sc = (t & 7) * 4, sr = t >> 3;   // staging: 32 k x 32 rows/pass

  float acc[8][8] = {};

  for (int k0 = 0; k0 < 128; k0 += 32) {
#pragma unroll
    for (int p = 0; p < 4; ++p) {
      int r = sr + p * 32;
      float4 a4 = *(const float4*)&A[(size_t)(m0 + r) * 128 + k0 + sc];
      float4 w4 = *(const float4*)&W[(size_t)(n0 + r) * 128 + k0 + sc];
      As[sc + 0][r] = a4.x; As[sc + 1][r] = a4.y;
      As[sc + 2][r] = a4.z; As[sc + 3][r] = a4.w;
      Bs[sc + 0][r] = w4.x; Bs[sc + 1][r] = w4.y;
      Bs[sc + 2][r] = w4.z; Bs[sc + 3][r] = w4.w;
    }
    __syncthreads();
#pragma unroll
    for (int kk = 0; kk < 32; ++kk) {
      float4 a0 = *(const float4*)&As[kk][ty * 4];
      float4 a1 = *(const float4*)&As[kk][ty * 4 + 64];
      float4 b0 = *(const float4*)&Bs[kk][tx * 4];
      float4 b1 = *(const float4*)&Bs[kk][tx * 4 + 64];
      float av[8] = {a0.x, a0.y, a0.z, a0.w, a1.x, a1.y, a1.z, a1.w};
      float bv[8] = {b0.x, b0.y, b0.z, b0.w, b1.x, b1.y, b1.z, b1.w};
#pragma unroll
      for (int i = 0; i < 8; ++i)
#pragma unroll
        for (int j = 0; j < 8; ++j)
          acc[i][j] = fmaf(av[i], bv[j], acc[i][j]);
    }
    __syncthreads();
  }

  const bool zhalf = (n0 >= 256);
#pragma unroll
  for (int ih = 0; ih < 2; ++ih)
#pragma unroll
    for (int i = 0; i < 4; ++i) {
      int m = m0 + ih * 64 + ty * 4 + i;
#pragma unroll
      for (int jh = 0; jh < 2; ++jh) {
        float4 c4 = make_float4(acc[ih*4+i][jh*4+0], acc[ih*4+i][jh*4+1],
                                acc[ih*4+i][jh*4+2], acc[ih*4+i][jh*4+3]);
        int n = n0 + jh * 64 + tx * 4;
        if (!zhalf) {
          *(float4*)&xa[(size_t)m * 256 + n] = c4;
        } else {
          c4.x = silu_f(c4.x); c4.y = silu_f(c4.y);
          c4.z = silu_f(c4.z); c4.w = silu_f(c4.w);
          *(float4*)&zs[(size_t)m * 256 + (n - 256)] = c4;
        }
      }
    }
}

// ---------------------------------------------------------------------------
// out_proj GEMM with fused y*silu(z) + y_t-transpose read, 128x128 tile,
// 8x8 per thread (same LDS-traffic halving as gemm_in).
// out[m,n] = sum_k (y_t[b,k,l] * zs[m,k]) * W[n,k],  m = b*LSEQ + l.
// Per 128-row tile all m share one b (128 | LSEQ). zs tile staged, then
// multiplied by y_t in LDS (coalesced over l) — fp32 product bit-identical
// to R13. Grid: (M/128, 1) since N = 128.
// ---------------------------------------------------------------------------
__global__ __launch_bounds__(256) void gemm_yz(
    const float* __restrict__ yT,      // [B,256,L]
    const float* __restrict__ zs,      // [M,256]
    const float* __restrict__ W,       // [128,256]
    float* __restrict__ out0)          // [M,128]
{
  __shared__ float As[32][132];
  __shared__ float Bs[32][132];
  const int m0 = blockIdx.x * 128;
  const int b  = m0 >> 12;             // m0 / LSEQ
  const int l0 = m0 & (LSEQ - 1);
  const int t  = threadIdx.x;
  const int tx = t & 15, ty = t >> 4;
  const int sc = (t & 7) * 4, sr = t >> 3;
  const int mm = t & 127, kq = t >> 7; // y-multiply mapping

  float acc[8][8] = {};

  for (int k0 = 0; k0 < 256; k0 += 32) {
#pragma unroll
    for (int p = 0; p < 4; ++p) {
      int r = sr + p * 32;
      float4 a4 = *(const float4*)&zs[(size_t)(m0 + r) * 256 + k0 + sc];
      float4 w4 = *(const float4*)&W[(size_t)r * 256 + k0 + sc];
      As[sc + 0][r] = a4.x; As[sc + 1][r] = a4.y;
      As[sc + 2][r] = a4.z; As[sc + 3][r] = a4.w;
      Bs[sc + 0][r] = w4.x; Bs[sc + 1][r] = w4.y;
      Bs[sc + 2][r] = w4.z; Bs[sc + 3][r] = w4.w;
    }
    __syncthreads();
    // As[k][mm] *= y_t[b, k0+k, l0+mm]  (coalesced over mm)
#pragma unroll
    for (int p = 0; p < 16; ++p) {
      int k = kq + p * 2;
      As[k][mm] *= yT[((size_t)(b * DINNER + k0 + k)) * LSEQ + l0 + mm];
    }
    __syncthreads();
#pragma unroll
    for (int kk = 0; kk < 32; ++kk) {
      float4 a0 = *(const float4*)&As[kk][ty * 4];
      float4 a1 = *(const float4*)&As[kk][ty * 4 + 64];
      float4 b0 = *(const float4*)&Bs[kk][tx * 4];
      float4 b1 = *(const float4*)&Bs[kk][tx * 4 + 64];
      float av[8] = {a0.x, a0.y, a0.z, a0.w, a1.x, a1.y, a1.z, a1.w};
      float bv[8] = {b0.x, b0.y, b0.z, b0.w, b1.x, b1.y, b1.z, b1.w};
#pragma unroll
      for (int i = 0; i < 8; ++i)
#pragma unroll
        for (int j = 0; j < 8; ++j)
          acc[i][j] = fmaf(av[i], bv[j], acc[i][j]);
    }
    __syncthreads();
  }

#pragma unroll
  for (int ih = 0; ih < 2; ++ih)
#pragma unroll
    for (int i = 0; i < 4; ++i) {
      int m = m0 + ih * 64 + ty * 4 + i;
#pragma unroll
      for (int jh = 0; jh < 2; ++jh) {
        float4 c4 = make_float4(acc[ih*4+i][jh*4+0], acc[ih*4+i][jh*4+1],
                                acc[ih*4+i][jh*4+2], acc[ih*4+i][jh*4+3]);
        int n = jh * 64 + tx * 4;
        *(float4*)&out0[(size_t)m * DMODEL + n] = c4;
      }
    }
}

// ---------------------------------------------------------------------------
// Causal depthwise conv (k=4) + bias + silu, with [M,256] -> [B,256,L] transpose
// ---------------------------------------------------------------------------
__global__ __launch_bounds__(256) void conv_silu_t(
    const float* __restrict__ xa_rm,   // [M,256]
    const float* __restrict__ cw,      // [256,4]
    const float* __restrict__ cb,      // [256]
    float* __restrict__ xa_t)          // [B,256,L]
{
  __shared__ float tile[64][133];      // [dd][li], li=0 ~ l0-3
  __shared__ float s_cw[64][4];
  __shared__ float s_cb[64];
  const int b  = blockIdx.z;
  const int d0 = blockIdx.y * 64;
  const int l0 = blockIdx.x * 128;
  const int t  = threadIdx.x;

  if (t < 64) {
    s_cb[t] = cb[d0 + t];
#pragma unroll
    for (int k = 0; k < 4; ++k) s_cw[t][k] = cw[(d0 + t) * 4 + k];
  }
  const int dd_st = t & 63;
  for (int li = t >> 6; li < 131; li += 4) {
    int l = l0 - 3 + li;
    float v = 0.f;
    if (l >= 0) v = xa_rm[((size_t)(b * LSEQ + l)) * 256 + d0 + dd_st];
    tile[dd_st][li] = v;
  }
  __syncthreads();

  for (int idx = t; idx < 64 * 128; idx += 256) {
    int dd = idx >> 7;
    int lc = idx & 127;
    float v = s_cb[dd]
            + tile[dd][lc + 0] * s_cw[dd][0]
            + tile[dd][lc + 1] * s_cw[dd][1]
            + tile[dd][lc + 2] * s_cw[dd][2]
            + tile[dd][lc + 3] * s_cw[dd][3];
    v = silu_f(v);
    xa_t[((size_t)(b * DINNER + d0 + dd)) * LSEQ + l0 + lc] = v;
  }
}

// ---------------------------------------------------------------------------
// Fused x_proj (40x256) + dt_proj (256x8) + softplus.
// Writes dt_t [B,256,L], Bt/Ct [B,16,L]  (state-major, L-contiguous).
// ---------------------------------------------------------------------------
__global__ __launch_bounds__(256) void proj_dt(
    const float* __restrict__ xa_t,    // [B,256,L]
    const float* __restrict__ xp_w,    // [40,256]
    const float* __restrict__ dtp_w,   // [256,8]
    const float* __restrict__ dtp_b,   // [256]
    float* __restrict__ dt_t,          // [B,256,L]
    float* __restrict__ Bt,            // [B,16,L]
    float* __restrict__ Ct)            // [B,16,L]
{
  __shared__ float s_xpc[40][68];
  __shared__ float s_dtw[256 * 8];
  __shared__ float s_dtb[256];
  __shared__ float s_xa[64][68];
  __shared__ float s_proj[64][44];
  const int b  = blockIdx.y;
  const int l0 = blockIdx.x * 64;
  const int t  = threadIdx.x;

  for (int i = t; i < 256 * 8; i += 256) s_dtw[i] = dtp_w[i];
  s_dtb[t] = dtp_b[t];

  const int ll_st  = t & 63;
  const int kk0_st = t >> 6;
  const int kk_w   = t & 63;
  const int nb_w   = t >> 6;
  const int lA = t & 31;
  const int g  = t >> 5;

  float acc0[5] = {}, acc1[5] = {};

  for (int kc = 0; kc < 256; kc += 64) {
    __syncthreads();
#pragma unroll
    for (int p = 0; p < 16; ++p) {
      int kk = kk0_st + p * 4;
      s_xa[ll_st][kk] =
          xa_t[((size_t)(b * DINNER + kc + kk)) * LSEQ + l0 + ll_st];
    }
#pragma unroll
    for (int p = 0; p < 10; ++p) {
      int n = nb_w + p * 4;
      s_xpc[n][kk_w] = xp_w[n * 256 + kc + kk_w];
    }
    __syncthreads();
#pragma unroll
    for (int kk = 0; kk < 64; kk += 4) {
      float4 a0 = *(const float4*)&s_xa[lA][kk];
      float4 a1 = *(const float4*)&s_xa[lA + 32][kk];
#pragma unroll
      for (int j = 0; j < 5; ++j) {
        float4 w4 = *(const float4*)&s_xpc[g * 5 + j][kk];
        acc0[j] = fmaf(a0.x, w4.x, fmaf(a0.y, w4.y,
                  fmaf(a0.z, w4.z, fmaf(a0.w, w4.w, acc0[j]))));
        acc1[j] = fmaf(a1.x, w4.x, fmaf(a1.y, w4.y,
                  fmaf(a1.z, w4.z, fmaf(a1.w, w4.w, acc1[j]))));
      }
    }
  }
  __syncthreads();
#pragma unroll
  for (int j = 0; j < 5; ++j) {
    s_proj[lA][g * 5 + j]      = acc0[j];
    s_proj[lA + 32][g * 5 + j] = acc1[j];
  }
  __syncthreads();

  const int ll = t & 63;
  const int dgroup = t >> 6;
  float4 p0 = *(const float4*)&s_proj[ll][0];
  float4 p1 = *(const float4*)&s_proj[ll][4];
  for (int j = 0; j < 64; ++j) {
    int dout = dgroup * 64 + j;
    float4 w0 = *(const float4*)&s_dtw[dout * 8];
    float4 w1 = *(const float4*)&s_dtw[dout * 8 + 4];
    float v = s_dtb[dout]
            + p0.x * w0.x + p0.y * w0.y + p0.z * w0.z + p0.w * w0.w
            + p1.x * w1.x + p1.y * w1.y + p1.z * w1.z + p1.w * w1.w;
    dt_t[((size_t)(b * DINNER + dout)) * LSEQ + l0 + ll] = softplus_f(v);
  }
  // Bt/Ct: [B,16,L] — 64 consecutive l-addresses per instruction (coalesced)
  if (t < 64) {
#pragma unroll
    for (int nn = 0; nn < 16; ++nn)
      Bt[((size_t)(b * NSTATE + nn)) * LSEQ + l0 + t] = s_proj[t][8 + nn];
  } else if (t < 128) {
    int lw = t - 64;
#pragma unroll
    for (int nn = 0; nn < 16; ++nn)
      Ct[((size_t)(b * NSTATE + nn)) * LSEQ + l0 + lw] = s_proj[lw][24 + nn];
  }
}

// ---------------------------------------------------------------------------
// Selective scan — EXACT R9 version (known-good: 158 µs/layer, absmax
// 1.746e-10). Sequential recurrence; __expf; DPP row_shr reduction.
// Deep register prefetch was tried 5 ways (R6 ring, R7 sched_barrier,
// R9 ring, R11/R12 inline-asm loads) — the compiler either sinks the loads
// (depth collapses to ~1) or RA inserts copies that race the in-flight asm
// loads (crashes). 158 µs is this structure's plateau; do not re-attempt
// register prefetch via source-level tricks.
// ---------------------------------------------------------------------------
__global__ __launch_bounds__(64) void scan_k(
    const float* __restrict__ dt_t, const float* __restrict__ u_t,
    const float* __restrict__ Bt,   const float* __restrict__ Ct,
    const float* __restrict__ A_log, const float* __restrict__ Dp,
    float* __restrict__ y_t)
{
  const int blk = blockIdx.x;
  const int b   = blk >> 6;
  const int d0  = (blk & 63) * 4;
  const int lane = threadIdx.x;
  const int g = lane >> 4;
  const int n = lane & 15;
  const int d = d0 + g;

  const float Aa = -expf(A_log[d * NSTATE + n]);   // once; keep libm here
  const float Dv = Dp[d];
  const float4* dtp = (const float4*)(dt_t + ((size_t)(b * DINNER + d)) * LSEQ);
  const float4* up  = (const float4*)(u_t  + ((size_t)(b * DINNER + d)) * LSEQ);
  const float4* Bp  = (const float4*)(Bt + ((size_t)(b * NSTATE + n)) * LSEQ);
  const float4* Cp  = (const float4*)(Ct + ((size_t)(b * NSTATE + n)) * LSEQ);
  float4* yp = (float4*)(y_t + ((size_t)(b * DINNER + d)) * LSEQ);

  const int NG = LSEQ / 8;             // 512 groups of 8 steps
  float4 Rd[4][2], Ru[4][2], Rb[4][2], Rc[4][2];
  float h = 0.f;

#define LOAD_GRP(s, grp) do {                                            \
    int _gg = (grp) < NG ? (grp) : NG - 1;                               \
    int _base = _gg * 2;                                                 \
    _Pragma("unroll")                                                    \
    for (int q = 0; q < 2; ++q) {                                        \
      Rd[s][q] = dtp[_base + q];  Ru[s][q] = up[_base + q];              \
      Rb[s][q] = Bp[_base + q];   Rc[s][q] = Cp[_base + q];              \
    }                                                                    \
  } while (0)

#define COMP_GRP(s, grp) do {                                            \
    float p[8], us8[8];                                                  \
    _Pragma("unroll")                                                    \
    for (int q = 0; q < 2; ++q) {                                        \
      float dts[4] = {Rd[s][q].x, Rd[s][q].y, Rd[s][q].z, Rd[s][q].w};   \
      float uq[4]  = {Ru[s][q].x, Ru[s][q].y, Ru[s][q].z, Ru[s][q].w};   \
      float bv[4]  = {Rb[s][q].x, Rb[s][q].y, Rb[s][q].z, Rb[s][q].w};   \
      float cv[4]  = {Rc[s][q].x, Rc[s][q].y, Rc[s][q].z, Rc[s][q].w};   \
      _Pragma("unroll")                                                  \
      for (int st = 0; st < 4; ++st) {                                   \
        int i = q * 4 + st;                                              \
        float a = __expf(dts[st] * Aa);                                  \
        h = fmaf(a, h, (dts[st] * uq[st]) * bv[st]);                     \
        p[i] = h * cv[st];                                               \
        us8[i] = uq[st];                                                 \
      }                                                                  \
    }                                                                    \
    /* 16-lane row reduction on VALU via DPP; sum lands at lane n==0 */  \
    _Pragma("unroll")                                                    \
    for (int i = 0; i < 8; ++i) p[i] += dpp_shift<0x118>(p[i]);          \
    _Pragma("unroll")                                                    \
    for (int i = 0; i < 8; ++i) p[i] += dpp_shift<0x114>(p[i]);          \
    _Pragma("unroll")                                                    \
    for (int i = 0; i < 8; ++i) p[i] += dpp_shift<0x112>(p[i]);          \
    _Pragma("unroll")                                                    \
    for (int i = 0; i < 8; ++i) p[i] += dpp_shift<0x111>(p[i]);          \
    if (n == 0) {                                                        \
      _Pragma("unroll")                                                  \
      for (int q = 0; q < 2; ++q)                                        \
        yp[(grp) * 2 + q] = make_float4(                                 \
            fmaf(us8[q*4+0], Dv, p[q*4+0]),                              \
            fmaf(us8[q*4+1], Dv, p[q*4+1]),                              \
            fmaf(us8[q*4+2], Dv, p[q*4+2]),                              \
            fmaf(us8[q*4+3], Dv, p[q*4+3]));                             \
    }                                                                    \
  } while (0)

  LOAD_GRP(0, 0);
  LOAD_GRP(1, 1);
  LOAD_GRP(2, 2);
  for (int it = 0; it < NG; it += 4) {
    LOAD_GRP(3, it + 3);
    COMP_GRP(0, it);
    LOAD_GRP(0, it + 4);
    COMP_GRP(1, it + 1);
    LOAD_GRP(1, it + 5);
    COMP_GRP(2, it + 2);
    LOAD_GRP(2, it + 6);
    COMP_GRP(3, it + 3);
  }
#undef LOAD_GRP
#undef COMP_GRP
}

// ---------------------------------------------------------------------------
extern "C" void kernel_launch(void* const* d_in, const int* in_sizes, int n_in,
                              void* d_out, int out_size, void* d_ws, size_t ws_size,
                              hipStream_t stream) {
  const float* x_in  = (const float*)d_in[0];
  const float* w_in  = (const float*)d_in[1];   // [4,512,128]
  const float* cw    = (const float*)d_in[2];   // [4,256,4]
  const float* cb    = (const float*)d_in[3];   // [4,256]
  const float* xpw   = (const float*)d_in[4];   // [4,40,256]
  const float* dtw   = (const float*)d_in[5];   // [4,256,8]
  const float* dtb   = (const float*)d_in[6];   // [4,256]
  const float* alog  = (const float*)d_in[7];   // [4,256,16]
  const float* Dp    = (const float*)d_in[8];   // [4,256]
  const float* ow    = (const float*)d_in[9];   // [4,128,256]
  float* out = (float*)d_out;

  const size_t M = MROWS;
  float* f0 = (float*)d_ws;            // x ping  [M,128]
  float* f1 = f0 + M * 128;            // x pong  [M,128]
  float* f2 = f1 + M * 128;            // xa_pre -> dt_t [B,256,L]
  float* f3 = f2 + M * 256;            // zs = silu(z) [M,256]
  float* f4 = f3 + M * 256;            // xa_t [B,256,L]
  float* f6 = f4 + M * 256;            // Bt [B,16,L]
  float* f7 = f6 + M * 16;             // Ct [B,16,L]
  float* f8 = f7 + M * 16;             // y_t [B,256,L]

  const float* cur = x_in;
  for (int i = 0; i < NLAYER; ++i) {
    float* xout = (i == NLAYER - 1) ? out : ((i % 2 == 0) ? f0 : f1);
    const float* wi  = w_in + (size_t)i * 512 * 128;
    const float* cwi = cw   + (size_t)i * 256 * 4;
    const float* cbi = cb   + (size_t)i * 256;
    const float* xpi = xpw  + (size_t)i * 40 * 256;
    const float* dwi = dtw  + (size_t)i * 256 * 8;
    const float* dbi = dtb  + (size_t)i * 256;
    const float* ali = alog + (size_t)i * 256 * 16;
    const float* dpi = Dp   + (size_t)i * 256;
    const float* owi = ow   + (size_t)i * 128 * 256;

    // 1. in_proj (128x128 tile): -> xa_pre(f2), silu(z)(f3)
    gemm_in<<<dim3(MROWS / 128, 4), 256, 0, stream>>>(cur, wi, f2, f3);
    // 2. conv + silu + transpose -> xa_t (f4)
    conv_silu_t<<<dim3(LSEQ / 128, DINNER / 64, BATCH), 256, 0, stream>>>(
        f2, cwi, cbi, f4);
    // 3. x_proj + dt_proj + softplus -> dt_t(f2), Bt(f6), Ct(f7)
    proj_dt<<<dim3(LSEQ / 64, BATCH), 256, 0, stream>>>(
        f4, xpi, dwi, dbi, f2, f6, f7);
    // 4. selective scan (exact R9) -> y_t (f8)
    scan_k<<<dim3(BATCH * DINNER / 4), 64, 0, stream>>>(
        f2, f4, f6, f7, ali, dpi, f8);
    // 5. out_proj (128x128 tile) with fused y*silu(z) + transpose -> xout
    gemm_yz<<<dim3(MROWS / 128, 1), 256, 0, stream>>>(f8, f3, owi, xout);

    cur = xout;
  }
}

// Round 15
// 1364.031 us; speedup vs baseline: 1.6301x; 1.0484x over previous
//
#include <hip/hip_runtime.h>
#include <cstddef>

#define BATCH   8
#define LSEQ    4096
#define DMODEL  128
#define DINNER  256
#define NSTATE  16
#define NLAYER  4
#define MROWS   (BATCH*LSEQ)   // 32768

__device__ __forceinline__ float silu_f(float v) { return v / (1.f + expf(-v)); }
__device__ __forceinline__ float softplus_f(float v) {
  return v > 20.f ? v : log1pf(expf(v));
}

// v_add_f32_dpp row_shr reduction step
template <int CTRL>
__device__ __forceinline__ float dpp_shift(float v) {
  int r = __builtin_amdgcn_update_dpp(0, __float_as_int(v), CTRL, 0xF, 0xF, true);
  return __int_as_float(r);
}

// ---------------------------------------------------------------------------
// in_proj GEMM: [M,128] @ [512,128]^T, 128x128 tile, 8x8 per thread.
// (unchanged from R14 — 2 FLOP/LDS-byte, bit-identical k-ascending fmaf)
// ---------------------------------------------------------------------------
__global__ __launch_bounds__(256) void gemm_in(
    const float* __restrict__ A,       // [M,128]
    const float* __restrict__ W,       // [512,128]
    float* __restrict__ xa,            // [M,256]
    float* __restrict__ zs)            // [M,256]
{
  __shared__ float As[32][132];
  __shared__ float Bs[32][132];
  const int m0 = blockIdx.x * 128;
  const int n0 = blockIdx.y * 128;
  const int t  = threadIdx.x;
  const int tx = t & 15, ty = t >> 4;
  const int sc = (t & 7) * 4, sr = t >> 3;

  float acc[8][8] = {};

  for (int k0 = 0; k0 < 128; k0 += 32) {
#pragma unroll
    for (int p = 0; p < 4; ++p) {
      int r = sr + p * 32;
      float4 a4 = *(const float4*)&A[(size_t)(m0 + r) * 128 + k0 + sc];
      float4 w4 = *(const float4*)&W[(size_t)(n0 + r) * 128 + k0 + sc];
      As[sc + 0][r] = a4.x; As[sc + 1][r] = a4.y;
      As[sc + 2][r] = a4.z; As[sc + 3][r] = a4.w;
      Bs[sc + 0][r] = w4.x; Bs[sc + 1][r] = w4.y;
      Bs[sc + 2][r] = w4.z; Bs[sc + 3][r] = w4.w;
    }
    __syncthreads();
#pragma unroll
    for (int kk = 0; kk < 32; ++kk) {
      float4 a0 = *(const float4*)&As[kk][ty * 4];
      float4 a1 = *(const float4*)&As[kk][ty * 4 + 64];
      float4 b0 = *(const float4*)&Bs[kk][tx * 4];
      float4 b1 = *(const float4*)&Bs[kk][tx * 4 + 64];
      float av[8] = {a0.x, a0.y, a0.z, a0.w, a1.x, a1.y, a1.z, a1.w};
      float bv[8] = {b0.x, b0.y, b0.z, b0.w, b1.x, b1.y, b1.z, b1.w};
#pragma unroll
      for (int i = 0; i < 8; ++i)
#pragma unroll
        for (int j = 0; j < 8; ++j)
          acc[i][j] = fmaf(av[i], bv[j], acc[i][j]);
    }
    __syncthreads();
  }

  const bool zhalf = (n0 >= 256);
#pragma unroll
  for (int ih = 0; ih < 2; ++ih)
#pragma unroll
    for (int i = 0; i < 4; ++i) {
      int m = m0 + ih * 64 + ty * 4 + i;
#pragma unroll
      for (int jh = 0; jh < 2; ++jh) {
        float4 c4 = make_float4(acc[ih*4+i][jh*4+0], acc[ih*4+i][jh*4+1],
                                acc[ih*4+i][jh*4+2], acc[ih*4+i][jh*4+3]);
        int n = n0 + jh * 64 + tx * 4;
        if (!zhalf) {
          *(float4*)&xa[(size_t)m * 256 + n] = c4;
        } else {
          c4.x = silu_f(c4.x); c4.y = silu_f(c4.y);
          c4.z = silu_f(c4.z); c4.w = silu_f(c4.w);
          *(float4*)&zs[(size_t)m * 256 + (n - 256)] = c4;
        }
      }
    }
}

// ---------------------------------------------------------------------------
// out_proj GEMM, fused y*silu(z) + y_t-transpose read. 64x128 tile, 4x8/thr.
// R14's 128x128 tile gave only 256 blocks = 1 wave/SIMD (no co-residency);
// 64x128 doubles the grid to 512 blocks (2 blocks/CU). Same k-ascending fmaf
// order and same zs*y product -> bit-identical to R14.
// ---------------------------------------------------------------------------
__global__ __launch_bounds__(256) void gemm_yz(
    const float* __restrict__ yT,      // [B,256,L]
    const float* __restrict__ zs,      // [M,256]
    const float* __restrict__ W,       // [128,256]
    float* __restrict__ out0)          // [M,128]
{
  __shared__ float As[32][68];
  __shared__ float Bs[32][132];
  const int m0 = blockIdx.x * 64;
  const int b  = m0 >> 12;             // m0 / LSEQ
  const int l0 = m0 & (LSEQ - 1);
  const int t  = threadIdx.x;
  const int tx = t & 15, ty = t >> 4;  // ty 0..15
  const int sc = (t & 7) * 4, sr = t >> 3;
  const int mm = t & 63, kq = t >> 6;

  float acc[4][8] = {};

  for (int k0 = 0; k0 < 256; k0 += 32) {
#pragma unroll
    for (int p = 0; p < 2; ++p) {
      int r = sr + p * 32;
      float4 a4 = *(const float4*)&zs[(size_t)(m0 + r) * 256 + k0 + sc];
      As[sc + 0][r] = a4.x; As[sc + 1][r] = a4.y;
      As[sc + 2][r] = a4.z; As[sc + 3][r] = a4.w;
    }
#pragma unroll
    for (int p = 0; p < 4; ++p) {
      int r = sr + p * 32;
      float4 w4 = *(const float4*)&W[(size_t)r * 256 + k0 + sc];
      Bs[sc + 0][r] = w4.x; Bs[sc + 1][r] = w4.y;
      Bs[sc + 2][r] = w4.z; Bs[sc + 3][r] = w4.w;
    }
    __syncthreads();
    // As[k][mm] *= y_t[b, k0+k, l0+mm]  (coalesced over mm)
#pragma unroll
    for (int p = 0; p < 8; ++p) {
      int k = kq + p * 4;
      As[k][mm] *= yT[((size_t)(b * DINNER + k0 + k)) * LSEQ + l0 + mm];
    }
    __syncthreads();
#pragma unroll
    for (int kk = 0; kk < 32; ++kk) {
      float4 a0 = *(const float4*)&As[kk][ty * 4];
      float4 b0 = *(const float4*)&Bs[kk][tx * 4];
      float4 b1 = *(const float4*)&Bs[kk][tx * 4 + 64];
      float av[4] = {a0.x, a0.y, a0.z, a0.w};
      float bv[8] = {b0.x, b0.y, b0.z, b0.w, b1.x, b1.y, b1.z, b1.w};
#pragma unroll
      for (int i = 0; i < 4; ++i)
#pragma unroll
        for (int j = 0; j < 8; ++j)
          acc[i][j] = fmaf(av[i], bv[j], acc[i][j]);
    }
    __syncthreads();
  }

#pragma unroll
  for (int i = 0; i < 4; ++i) {
    int m = m0 + ty * 4 + i;
#pragma unroll
    for (int jh = 0; jh < 2; ++jh) {
      float4 c4 = make_float4(acc[i][jh*4+0], acc[i][jh*4+1],
                              acc[i][jh*4+2], acc[i][jh*4+3]);
      *(float4*)&out0[(size_t)m * DMODEL + jh * 64 + tx * 4] = c4;
    }
  }
}

// ---------------------------------------------------------------------------
// FUSED conv + x_proj + dt_proj + softplus (conv_silu_t eliminated).
// Per 64-l-tile, per 64-col k-chunk: stage PRE-conv rows l0-3..l0+63 (s_pre,
// 69-pad -> conflict-free scalar reads), apply conv+silu with the identical
// left-assoc fp-contracted expression into s_xa (bit-identical values to the
// old conv_silu_t), write xa_t out coalesced (scan's u), and accumulate the
// x_proj from s_xa exactly as before. dt epilogue/Bt/Ct unchanged.
// s_pre aliases s_proj (disjoint lifetimes) to keep LDS ~56 KB.
// ---------------------------------------------------------------------------
__global__ __launch_bounds__(256) void convproj_dt(
    const float* __restrict__ xa_pre,  // [M,256] pre-conv (gemm_in output)
    const float* __restrict__ cw,      // [256,4]
    const float* __restrict__ cb,      // [256]
    const float* __restrict__ xp_w,    // [40,256]
    const float* __restrict__ dtp_w,   // [256,8]
    const float* __restrict__ dtp_b,   // [256]
    float* __restrict__ xa_t,          // [B,256,L]  (u for scan)
    float* __restrict__ dt_t,          // [B,256,L]
    float* __restrict__ Bt,            // [B,16,L]
    float* __restrict__ Ct)            // [B,16,L]
{
  __shared__ float s_buf[67 * 69];     // s_pre in k-loop; s_proj after
  __shared__ float s_xpc[40][68];
  __shared__ float s_dtw[256 * 8];
  __shared__ float s_dtb[256];
  __shared__ float s_xa[64][68];
  float (*s_pre)[69]  = (float(*)[69])s_buf;
  float (*s_proj)[44] = (float(*)[44])s_buf;

  const int b  = blockIdx.y;
  const int l0 = blockIdx.x * 64;
  const int t  = threadIdx.x;

  for (int i = t; i < 256 * 8; i += 256) s_dtw[i] = dtp_w[i];
  s_dtb[t] = dtp_b[t];

  const int c_st = t & 63;             // staging / conv column
  const int r_st = t >> 6;
  const int lA = t & 31;
  const int g  = t >> 5;

  float acc0[5] = {}, acc1[5] = {};

  for (int kc = 0; kc < 256; kc += 64) {
    __syncthreads();
    // stage pre-conv rows l0-3 .. l0+63, cols kc..kc+63
    for (int r = r_st; r < 67; r += 4) {
      int l = l0 - 3 + r;
      float v = 0.f;
      if (l >= 0) v = xa_pre[((size_t)b * LSEQ + l) * 256 + kc + c_st];
      s_pre[r][c_st] = v;
    }
#pragma unroll
    for (int p = 0; p < 10; ++p) {
      int n = r_st + p * 4;
      s_xpc[n][c_st] = xp_w[n * 256 + kc + c_st];
    }
    __syncthreads();
    // conv + silu -> s_xa (same expression tree as conv_silu_t)
    {
      const int kk = c_st;
      float w0 = cw[(kc + kk) * 4 + 0], w1 = cw[(kc + kk) * 4 + 1];
      float w2 = cw[(kc + kk) * 4 + 2], w3 = cw[(kc + kk) * 4 + 3];
      float cbr = cb[kc + kk];
#pragma unroll
      for (int p = 0; p < 16; ++p) {
        int ll = r_st + p * 4;
        float v = cbr
                + s_pre[ll + 0][kk] * w0
                + s_pre[ll + 1][kk] * w1
                + s_pre[ll + 2][kk] * w2
                + s_pre[ll + 3][kk] * w3;
        s_xa[ll][kk] = silu_f(v);
      }
    }
    __syncthreads();
    // write xa_t coalesced (64 consecutive l per instruction)
    {
      const int lw = c_st;
#pragma unroll
      for (int p = 0; p < 16; ++p) {
        int kw = r_st + p * 4;
        xa_t[((size_t)(b * DINNER + kc + kw)) * LSEQ + l0 + lw] = s_xa[lw][kw];
      }
    }
    // x_proj accumulate (identical to the old proj_dt)
#pragma unroll
    for (int kk = 0; kk < 64; kk += 4) {
      float4 a0 = *(const float4*)&s_xa[lA][kk];
      float4 a1 = *(const float4*)&s_xa[lA + 32][kk];
#pragma unroll
      for (int j = 0; j < 5; ++j) {
        float4 w4 = *(const float4*)&s_xpc[g * 5 + j][kk];
        acc0[j] = fmaf(a0.x, w4.x, fmaf(a0.y, w4.y,
                  fmaf(a0.z, w4.z, fmaf(a0.w, w4.w, acc0[j]))));
        acc1[j] = fmaf(a1.x, w4.x, fmaf(a1.y, w4.y,
                  fmaf(a1.z, w4.z, fmaf(a1.w, w4.w, acc1[j]))));
      }
    }
  }
  __syncthreads();
#pragma unroll
  for (int j = 0; j < 5; ++j) {
    s_proj[lA][g * 5 + j]      = acc0[j];
    s_proj[lA + 32][g * 5 + j] = acc1[j];
  }
  __syncthreads();

  const int ll = t & 63;
  const int dgroup = t >> 6;
  float4 p0 = *(const float4*)&s_proj[ll][0];
  float4 p1 = *(const float4*)&s_proj[ll][4];
  for (int j = 0; j < 64; ++j) {
    int dout = dgroup * 64 + j;
    float4 w0 = *(const float4*)&s_dtw[dout * 8];
    float4 w1 = *(const float4*)&s_dtw[dout * 8 + 4];
    float v = s_dtb[dout]
            + p0.x * w0.x + p0.y * w0.y + p0.z * w0.z + p0.w * w0.w
            + p1.x * w1.x + p1.y * w1.y + p1.z * w1.z + p1.w * w1.w;
    dt_t[((size_t)(b * DINNER + dout)) * LSEQ + l0 + ll] = softplus_f(v);
  }
  if (t < 64) {
#pragma unroll
    for (int nn = 0; nn < 16; ++nn)
      Bt[((size_t)(b * NSTATE + nn)) * LSEQ + l0 + t] = s_proj[t][8 + nn];
  } else if (t < 128) {
    int lw = t - 64;
#pragma unroll
    for (int nn = 0; nn < 16; ++nn)
      Ct[((size_t)(b * NSTATE + nn)) * LSEQ + l0 + lw] = s_proj[lw][24 + nn];
  }
}

// ---------------------------------------------------------------------------
// Selective scan — EXACT R9 version (plateau: ~160 µs/layer, absmax
// 1.746e-10). dt is read from and y written to the SAME buffer (f8):
// safe because each (b,d) row is owned by one block and prefetch l-ranges
// always lead the y-write l-ranges. Do not re-attempt register prefetch.
// ---------------------------------------------------------------------------
__global__ __launch_bounds__(64) void scan_k(
    const float* __restrict__ dt_t, const float* __restrict__ u_t,
    const float* __restrict__ Bt,   const float* __restrict__ Ct,
    const float* __restrict__ A_log, const float* __restrict__ Dp,
    float* __restrict__ y_t)
{
  const int blk = blockIdx.x;
  const int b   = blk >> 6;
  const int d0  = (blk & 63) * 4;
  const int lane = threadIdx.x;
  const int g = lane >> 4;
  const int n = lane & 15;
  const int d = d0 + g;

  const float Aa = -expf(A_log[d * NSTATE + n]);
  const float Dv = Dp[d];
  const float4* dtp = (const float4*)(dt_t + ((size_t)(b * DINNER + d)) * LSEQ);
  const float4* up  = (const float4*)(u_t  + ((size_t)(b * DINNER + d)) * LSEQ);
  const float4* Bp  = (const float4*)(Bt + ((size_t)(b * NSTATE + n)) * LSEQ);
  const float4* Cp  = (const float4*)(Ct + ((size_t)(b * NSTATE + n)) * LSEQ);
  float4* yp = (float4*)(y_t + ((size_t)(b * DINNER + d)) * LSEQ);

  const int NG = LSEQ / 8;
  float4 Rd[4][2], Ru[4][2], Rb[4][2], Rc[4][2];
  float h = 0.f;

#define LOAD_GRP(s, grp) do {                                            \
    int _gg = (grp) < NG ? (grp) : NG - 1;                               \
    int _base = _gg * 2;                                                 \
    _Pragma("unroll")                                                    \
    for (int q = 0; q < 2; ++q) {                                        \
      Rd[s][q] = dtp[_base + q];  Ru[s][q] = up[_base + q];              \
      Rb[s][q] = Bp[_base + q];   Rc[s][q] = Cp[_base + q];              \
    }                                                                    \
  } while (0)

#define COMP_GRP(s, grp) do {                                            \
    float p[8], us8[8];                                                  \
    _Pragma("unroll")                                                    \
    for (int q = 0; q < 2; ++q) {                                        \
      float dts[4] = {Rd[s][q].x, Rd[s][q].y, Rd[s][q].z, Rd[s][q].w};   \
      float uq[4]  = {Ru[s][q].x, Ru[s][q].y, Ru[s][q].z, Ru[s][q].w};   \
      float bv[4]  = {Rb[s][q].x, Rb[s][q].y, Rb[s][q].z, Rb[s][q].w};   \
      float cv[4]  = {Rc[s][q].x, Rc[s][q].y, Rc[s][q].z, Rc[s][q].w};   \
      _Pragma("unroll")                                                  \
      for (int st = 0; st < 4; ++st) {                                   \
        int i = q * 4 + st;                                              \
        float a = __expf(dts[st] * Aa);                                  \
        h = fmaf(a, h, (dts[st] * uq[st]) * bv[st]);                     \
        p[i] = h * cv[st];                                               \
        us8[i] = uq[st];                                                 \
      }                                                                  \
    }                                                                    \
    _Pragma("unroll")                                                    \
    for (int i = 0; i < 8; ++i) p[i] += dpp_shift<0x118>(p[i]);          \
    _Pragma("unroll")                                                    \
    for (int i = 0; i < 8; ++i) p[i] += dpp_shift<0x114>(p[i]);          \
    _Pragma("unroll")                                                    \
    for (int i = 0; i < 8; ++i) p[i] += dpp_shift<0x112>(p[i]);          \
    _Pragma("unroll")                                                    \
    for (int i = 0; i < 8; ++i) p[i] += dpp_shift<0x111>(p[i]);          \
    if (n == 0) {                                                        \
      _Pragma("unroll")                                                  \
      for (int q = 0; q < 2; ++q)                                        \
        yp[(grp) * 2 + q] = make_float4(                                 \
            fmaf(us8[q*4+0], Dv, p[q*4+0]),                              \
            fmaf(us8[q*4+1], Dv, p[q*4+1]),                              \
            fmaf(us8[q*4+2], Dv, p[q*4+2]),                              \
            fmaf(us8[q*4+3], Dv, p[q*4+3]));                             \
    }                                                                    \
  } while (0)

  LOAD_GRP(0, 0);
  LOAD_GRP(1, 1);
  LOAD_GRP(2, 2);
  for (int it = 0; it < NG; it += 4) {
    LOAD_GRP(3, it + 3);
    COMP_GRP(0, it);
    LOAD_GRP(0, it + 4);
    COMP_GRP(1, it + 1);
    LOAD_GRP(1, it + 5);
    COMP_GRP(2, it + 2);
    LOAD_GRP(2, it + 6);
    COMP_GRP(3, it + 3);
  }
#undef LOAD_GRP
#undef COMP_GRP
}

// ---------------------------------------------------------------------------
extern "C" void kernel_launch(void* const* d_in, const int* in_sizes, int n_in,
                              void* d_out, int out_size, void* d_ws, size_t ws_size,
                              hipStream_t stream) {
  const float* x_in  = (const float*)d_in[0];
  const float* w_in  = (const float*)d_in[1];   // [4,512,128]
  const float* cw    = (const float*)d_in[2];   // [4,256,4]
  const float* cb    = (const float*)d_in[3];   // [4,256]
  const float* xpw   = (const float*)d_in[4];   // [4,40,256]
  const float* dtw   = (const float*)d_in[5];   // [4,256,8]
  const float* dtb   = (const float*)d_in[6];   // [4,256]
  const float* alog  = (const float*)d_in[7];   // [4,256,16]
  const float* Dp    = (const float*)d_in[8];   // [4,256]
  const float* ow    = (const float*)d_in[9];   // [4,128,256]
  float* out = (float*)d_out;

  const size_t M = MROWS;
  float* f0 = (float*)d_ws;            // x ping  [M,128]
  float* f1 = f0 + M * 128;            // x pong  [M,128]
  float* f2 = f1 + M * 128;            // xa_pre [M,256] (stays live through convproj)
  float* f3 = f2 + M * 256;            // zs = silu(z) [M,256]
  float* f4 = f3 + M * 256;            // xa_t = u [B,256,L]
  float* f6 = f4 + M * 256;            // Bt [B,16,L]
  float* f7 = f6 + M * 16;             // Ct [B,16,L]
  float* f8 = f7 + M * 16;             // dt_t -> y_t (in-place) [B,256,L]

  const float* cur = x_in;
  for (int i = 0; i < NLAYER; ++i) {
    float* xout = (i == NLAYER - 1) ? out : ((i % 2 == 0) ? f0 : f1);
    const float* wi  = w_in + (size_t)i * 512 * 128;
    const float* cwi = cw   + (size_t)i * 256 * 4;
    const float* cbi = cb   + (size_t)i * 256;
    const float* xpi = xpw  + (size_t)i * 40 * 256;
    const float* dwi = dtw  + (size_t)i * 256 * 8;
    const float* dbi = dtb  + (size_t)i * 256;
    const float* ali = alog + (size_t)i * 256 * 16;
    const float* dpi = Dp   + (size_t)i * 256;
    const float* owi = ow   + (size_t)i * 128 * 256;

    // 1. in_proj (128x128 tile): -> xa_pre(f2), silu(z)(f3)
    gemm_in<<<dim3(MROWS / 128, 4), 256, 0, stream>>>(cur, wi, f2, f3);
    // 2. fused conv + x_proj + dt_proj -> xa_t(f4), dt_t(f8), Bt(f6), Ct(f7)
    convproj_dt<<<dim3(LSEQ / 64, BATCH), 256, 0, stream>>>(
        f2, cwi, cbi, xpi, dwi, dbi, f4, f8, f6, f7);
    // 3. selective scan (exact R9) -> y_t in-place over dt_t (f8)
    scan_k<<<dim3(BATCH * DINNER / 4), 64, 0, stream>>>(
        f8, f4, f6, f7, ali, dpi, f8);
    // 4. out_proj (64x128 tile) with fused y*silu(z) + transpose -> xout
    gemm_yz<<<dim3(MROWS / 64, 1), 256, 0, stream>>>(f8, f3, owi, xout);

    cur = xout;
  }
}